// Round 5
// baseline (3506.004 us; speedup 1.0000x reference)
//
#include <hip/hip_runtime.h>
#include <hip/hip_bf16.h>
#include <hip/hip_fp16.h>

// SeaReader forward, MI355X. Round 13: k_rec sequence-pairing (S=2 per block).
// Rounds 9-12 tried to make the 393KB whh matrix register-resident and lost to
// the register allocator four ways (infeasible geometry / SROA scratch / RA
// spill / AGPR container crash). New approach keeps the r8 streaming pattern
// (which the compiler compiles well: 0 conflicts, no spill) but runs TWO
// sequences per block: each streamed weight uint4 feeds hh-FMAs for both
// h-vectors, halving the per-sequence weight stream (the measured 4100cyc/step
// bottleneck at ~96B/cyc/CU). Step ~2400-2800cyc serving 2 seqs => ~1.6-2x on
// all three k_rec launches regardless of whether the wall is aggregate-L2 BW
// or per-CU delivery. Stmt seqs (16, T=256) stay S=1 to keep ctx makespan low.
// B=4 O=4 L=128 N=8 V=256 H=256; Ls=256; BO=16; BON=128. ws ~103 MB.

typedef unsigned short u16;
typedef unsigned int u32;
typedef __attribute__((ext_vector_type(8))) short short8;
typedef __attribute__((ext_vector_type(4))) float floatx4;

__device__ __forceinline__ float bf2f(u16 v) { return __uint_as_float(((u32)v) << 16); }
__device__ __forceinline__ u16 f2b(float f) {
  u32 u = __float_as_uint(f);
  return (u16)((u + 0x7fffu + ((u >> 16) & 1u)) >> 16);  // RNE; finite inputs only
}
__device__ __forceinline__ float ldf(u16 v) { return bf2f(v); }
__device__ __forceinline__ float ldf(float v) { return v; }
__device__ __forceinline__ void stf(u16* p, float v) { *p = f2b(v); }
__device__ __forceinline__ void stf(float* p, float v) { *p = v; }
__device__ __forceinline__ float ldraw(const void* p, size_t i, int isf) {
  return isf ? ((const float*)p)[i] : bf2f(((const u16*)p)[i]);
}
__device__ __forceinline__ __half2 u2h(u32 v) {
  union { u32 u; __half2 h; } c; c.u = v; return c.h;
}

// ---------------- dtype detection ----------------
__global__ void k_detect(const void* __restrict__ stmt, int* __restrict__ flag) {
  if (threadIdx.x == 0 && blockIdx.x == 0) {
    const float* f = (const float*)stmt;
    int sane = 0;
    for (int i = 0; i < 64; ++i) {
      const float a = fabsf(f[i]);
      if (a > 1e-20f && a < 1e6f) sane++;
    }
    *flag = (sane >= 48) ? 1 : 0;
  }
}

// ---------------- convert raw input to bf16 ----------------
__global__ __launch_bounds__(256) void k_cvt(const void* __restrict__ in, u16* __restrict__ out,
                                             int n, const int* __restrict__ flag) {
  const int isf = *flag;
  const int i = blockIdx.x * 256 + threadIdx.x;
  if (i < n) out[i] = f2b(ldraw(in, i, isf));
}

// ---------------- gather stmt = cat(question, answer) -> bf16 ----------------
__global__ __launch_bounds__(256) void k_gather_stmt(const void* __restrict__ statement,
                                                     const void* __restrict__ answer,
                                                     u16* __restrict__ out,
                                                     const int* __restrict__ flag) {
  const int isf = *flag;
  const int idx = blockIdx.x * 256 + threadIdx.x;  // < 16*256*256
  const int v = idx & 255;
  const int s = (idx >> 8) & 255;
  const int bo = idx >> 16;
  float val;
  if (s < 128) val = ldraw(statement, (size_t)(((bo >> 2) * 128) + s) * 256 + v, isf);
  else         val = ldraw(answer, (size_t)((bo * 128) + (s - 128)) * 256 + v, isf);
  out[idx] = f2b(val);
}

// ---- pack whh [768][256] -> fp16 half2 in [k8][768][4] u32 (thread-contiguous uint4) ----
// Gate-row r's chunk i (covering h[8i..8i+8)) = uint4 at index i*768 + r.
__global__ __launch_bounds__(256) void k_packh(const void* __restrict__ in, u32* __restrict__ out,
                                               int total, const int* __restrict__ flag) {
  const int isf = *flag;
  const int idx = blockIdx.x * 256 + threadIdx.x;  // over 768*128 (row, k2)
  if (idx >= total) return;
  const int r = idx % 768;
  const int k2 = idx / 768;
  const float a = ldraw(in, (size_t)r * 256 + 2 * k2, isf);
  const float b = ldraw(in, (size_t)r * 256 + 2 * k2 + 1, isf);
  const __half2 h2 = __floats2half2_rn(a, b);
  out[(((size_t)(k2 >> 2) * 768) + r) * 4 + (k2 & 3)] = *reinterpret_cast<const u32*>(&h2);
}

// ---------------- recurrent GRU core: xg precomputed; S sequences per block ----------------
// 768 threads = gate-rows; block processes S (1 or 2) sequences sharing the whh
// stream: each streamed weight uint4 feeds hh-FMAs for both h-vectors. Dual-job
// launch plumbing (two independent GRU groups per launch).
#define HH1(i)                                                              \
  {                                                                         \
    const uint4 wv = wp[(i) * 768];                                         \
    const uint4 hA = *reinterpret_cast<const uint4*>(&hsA_h[(i) * 8]);      \
    a0 = __hfma2(u2h(wv.x), u2h(hA.x), a0);                                 \
    a1 = __hfma2(u2h(wv.y), u2h(hA.y), a1);                                 \
    a2 = __hfma2(u2h(wv.z), u2h(hA.z), a2);                                 \
    a3 = __hfma2(u2h(wv.w), u2h(hA.w), a3);                                 \
  }
#define HH2(i)                                                              \
  {                                                                         \
    const uint4 wv = wp[(i) * 768];                                         \
    const uint4 hA = *reinterpret_cast<const uint4*>(&hsA_h[(i) * 8]);      \
    const uint4 hB = *reinterpret_cast<const uint4*>(&hsB_h[(i) * 8]);      \
    a0 = __hfma2(u2h(wv.x), u2h(hA.x), a0);                                 \
    a1 = __hfma2(u2h(wv.y), u2h(hA.y), a1);                                 \
    a2 = __hfma2(u2h(wv.z), u2h(hA.z), a2);                                 \
    a3 = __hfma2(u2h(wv.w), u2h(hA.w), a3);                                 \
    b0 = __hfma2(u2h(wv.x), u2h(hB.x), b0);                                 \
    b1 = __hfma2(u2h(wv.y), u2h(hB.y), b1);                                 \
    b2 = __hfma2(u2h(wv.z), u2h(hB.z), b2);                                 \
    b3 = __hfma2(u2h(wv.w), u2h(hB.w), b3);                                 \
  }

__global__ __attribute__((amdgpu_flat_work_group_size(768, 768)))
void k_rec(
    const u16* __restrict__ xg0, const u32* __restrict__ whh0,
    const u16* __restrict__ bih0, const u16* __restrict__ bhh0,
    u16* __restrict__ oseq0, float* __restrict__ omax0, int nblk0, int S0, int T0,
    const u16* __restrict__ xg1, const u32* __restrict__ whh1,
    const u16* __restrict__ bih1, const u16* __restrict__ bhh1,
    u16* __restrict__ oseq1, float* __restrict__ omax1, int S1, int T1) {
  __shared__ __align__(16) float hsA_f[256];
  __shared__ __align__(16) float hsB_f[256];
  __shared__ __align__(16) __half hsA_h[256];
  __shared__ __align__(16) __half hsB_h[256];
  __shared__ __align__(16) float shA[768];
  __shared__ __align__(16) float shB[768];
  const u16 *xg, *bih, *bhh; const u32* whh; u16* oseq; float* omax; int T, S, blk;
  if ((int)blockIdx.x < nblk0) {
    blk = blockIdx.x; xg = xg0; whh = whh0; bih = bih0; bhh = bhh0;
    oseq = oseq0; omax = omax0; T = T0; S = S0;
  } else {
    blk = blockIdx.x - nblk0; xg = xg1; whh = whh1; bih = bih1; bhh = bhh1;
    oseq = oseq1; omax = omax1; T = T1; S = S1;
  }
  const int t = threadIdx.x;        // 0..767 (gate row)
  const bool dual = (S == 2);
  const int seqA = blk * S;
  const uint4* wp = reinterpret_cast<const uint4*>(whh) + t;
  const float bh = bf2f(bhh[t]);
  // per-thread elementwise role: t<256 -> seq A element t; 256<=t<512 (dual) -> seq B element t-256
  float bir = 0.f, biz = 0.f, bin = 0.f;
  if (t < 256) {
    bir = bf2f(bih[t]); biz = bf2f(bih[t + 256]); bin = bf2f(bih[t + 512]);
    hsA_f[t] = 0.f; hsA_h[t] = __float2half(0.f);
  } else if (dual && t < 512) {
    const int e = t - 256;
    bir = bf2f(bih[e]); biz = bf2f(bih[e + 256]); bin = bf2f(bih[e + 512]);
    hsB_f[e] = 0.f; hsB_h[e] = __float2half(0.f);
  }
  float vmax = -3.4e38f;
  const u16* xrowA = xg + (size_t)seqA * T * 768;
  const u16* xrowB = xg + (size_t)(seqA + 1) * T * 768;
  for (int st = 0; st < T; ++st, xrowA += 768, xrowB += 768) {
    float xr = 0.f, xz = 0.f, xn = 0.f;
    if (t < 256) {          // prefetch seq A x-gates
      xr = bf2f(xrowA[t]); xz = bf2f(xrowA[t + 256]); xn = bf2f(xrowA[t + 512]);
    } else if (dual && t < 512) {  // prefetch seq B x-gates
      const int e = t - 256;
      xr = bf2f(xrowB[e]); xz = bf2f(xrowB[e + 256]); xn = bf2f(xrowB[e + 512]);
    }
    __syncthreads();  // B1: prev-step h updates visible
    const __half2 z2 = __floats2half2_rn(0.f, 0.f);
    __half2 a0 = z2, a1 = z2, a2 = z2, a3 = z2;
    __half2 b0 = z2, b1 = z2, b2 = z2, b3 = z2;
    if (dual) {
      HH2(0)  HH2(1)  HH2(2)  HH2(3)  HH2(4)  HH2(5)  HH2(6)  HH2(7)
      HH2(8)  HH2(9)  HH2(10) HH2(11) HH2(12) HH2(13) HH2(14) HH2(15)
      HH2(16) HH2(17) HH2(18) HH2(19) HH2(20) HH2(21) HH2(22) HH2(23)
      HH2(24) HH2(25) HH2(26) HH2(27) HH2(28) HH2(29) HH2(30) HH2(31)
    } else {
      HH1(0)  HH1(1)  HH1(2)  HH1(3)  HH1(4)  HH1(5)  HH1(6)  HH1(7)
      HH1(8)  HH1(9)  HH1(10) HH1(11) HH1(12) HH1(13) HH1(14) HH1(15)
      HH1(16) HH1(17) HH1(18) HH1(19) HH1(20) HH1(21) HH1(22) HH1(23)
      HH1(24) HH1(25) HH1(26) HH1(27) HH1(28) HH1(29) HH1(30) HH1(31)
    }
    const float sA = (__low2float(a0) + __high2float(a0)) + (__low2float(a1) + __high2float(a1))
                   + (__low2float(a2) + __high2float(a2)) + (__low2float(a3) + __high2float(a3));
    shA[t] = sA + bh;
    if (dual) {
      const float sB = (__low2float(b0) + __high2float(b0)) + (__low2float(b1) + __high2float(b1))
                     + (__low2float(b2) + __high2float(b2)) + (__low2float(b3) + __high2float(b3));
      shB[t] = sB + bh;
    }
    __syncthreads();  // B2: sh visible; h reads done
    if (t < 256) {
      const float r = 1.f / (1.f + __expf(-(xr + bir + shA[t])));
      const float z = 1.f / (1.f + __expf(-(xz + biz + shA[t + 256])));
      const float n = tanhf(xn + bin + r * shA[t + 512]);
      const float hnew = (1.f - z) * n + z * hsA_f[t];
      hsA_f[t] = hnew;
      hsA_h[t] = __float2half(hnew);
      if (oseq) oseq[(size_t)(seqA * T + st) * 256 + t] = f2b(hnew);
      vmax = fmaxf(vmax, hnew);
    } else if (dual && t < 512) {
      const int e = t - 256;
      const float r = 1.f / (1.f + __expf(-(xr + bir + shB[e])));
      const float z = 1.f / (1.f + __expf(-(xz + biz + shB[e + 256])));
      const float n = tanhf(xn + bin + r * shB[e + 512]);
      const float hnew = (1.f - z) * n + z * hsB_f[e];
      hsB_f[e] = hnew;
      hsB_h[e] = __float2half(hnew);
      if (oseq) oseq[(size_t)((seqA + 1) * T + st) * 256 + e] = f2b(hnew);
      vmax = fmaxf(vmax, hnew);
    }
    // next B1 fences the h updates against next step's reads
  }
  if (omax) {
    if (t < 256) omax[(size_t)seqA * 256 + t] = vmax;
    else if (dual && t < 512) omax[(size_t)(seqA + 1) * 256 + (t - 256)] = vmax;
  }
}

// ---------- MFMA bf16 GEMM: C = A * (BT ? B^T : B) (+C), 64x64 tile, 4 waves ----------
// Fragment-order LDS: As[(w*64+lane)*8+j] = A[m0+16w+(lane&15)][k0+8*(lane>>4)+j]
//                     Bs[(nt*64+lane)*8+j] = B[k0+8*(lane>>4)+j][n0+16nt+(lane&15)]
// MFMA layouts per verified notes: A[m=lane&15][k=quad*8+j]; B[k=quad*8+j][n=lane&15];
// D: row=quad*4+reg, col=lane&15.
template <bool BT, bool CADD, typename TA, typename TB, typename TC>
__global__ __launch_bounds__(256) void k_mgemm(
    const TA* __restrict__ Abase, int lda, long strideA, int divA,
    const TB* __restrict__ Bbase, int ldb, long strideB, int divB,
    TC* __restrict__ Cbase, int ldc, long strideC, int K) {
  const int z = blockIdx.z;
  const TA* A = Abase + (size_t)(z / divA) * strideA;
  const TB* Bp = Bbase + (size_t)(z / divB) * strideB;
  TC* C = Cbase + (size_t)z * strideC;
  const int m0 = blockIdx.y << 6, n0 = blockIdx.x << 6;
  __shared__ __align__(16) u16 As[2048];
  __shared__ __align__(16) u16 Bs[2048];
  const int t = threadIdx.x;
  const int lane = t & 63, w = t >> 6;
  floatx4 acc0 = {0.f, 0.f, 0.f, 0.f};
  floatx4 acc1 = {0.f, 0.f, 0.f, 0.f};
  floatx4 acc2 = {0.f, 0.f, 0.f, 0.f};
  floatx4 acc3 = {0.f, 0.f, 0.f, 0.f};
  const int ar = t >> 2;                 // A/BT row (m or n local, 0..63)
  const int ac = (t & 3) << 3;           // k col8
  const int adst = (((ar >> 4) << 6) | (ar & 15) | ((t & 3) << 4)) << 3;
  const int bk = t >> 3;                 // non-BT: k row (0..31)
  const int bn = (t & 7) << 3;           // non-BT: n col8
  for (int k0 = 0; k0 < K; k0 += 32) {
    // stage A[64m][32k] in fragment order
    {
      const TA* ap = A + (size_t)(m0 + ar) * lda + (k0 + ac);
      if constexpr (sizeof(TA) == 2) {
        *reinterpret_cast<uint4*>(&As[adst]) = *reinterpret_cast<const uint4*>(ap);
      } else {
        const float4 f0 = reinterpret_cast<const float4*>(ap)[0];
        const float4 f1 = reinterpret_cast<const float4*>(ap)[1];
        u16* d = &As[adst];
        d[0] = f2b(f0.x); d[1] = f2b(f0.y); d[2] = f2b(f0.z); d[3] = f2b(f0.w);
        d[4] = f2b(f1.x); d[5] = f2b(f1.y); d[6] = f2b(f1.z); d[7] = f2b(f1.w);
      }
    }
    // stage B in fragment order
    if constexpr (BT) {
      const TB* bp = Bp + (size_t)(n0 + ar) * ldb + (k0 + ac);
      *reinterpret_cast<uint4*>(&Bs[adst]) = *reinterpret_cast<const uint4*>(bp);
    } else {
      const TB* bp = Bp + (size_t)(k0 + bk) * ldb + (n0 + bn);
      const uint4 v = *reinterpret_cast<const uint4*>(bp);
      const u16* pv = reinterpret_cast<const u16*>(&v);
#pragma unroll
      for (int j = 0; j < 8; ++j) {
        const int n = bn + j;
        Bs[(((((n >> 4) << 6) | (n & 15) | ((bk >> 3) << 4)) << 3) | (bk & 7))] = pv[j];
      }
    }
    __syncthreads();
    const short8 af = *reinterpret_cast<const short8*>(&As[(w * 64 + lane) << 3]);
    const short8 b0 = *reinterpret_cast<const short8*>(&Bs[(lane) << 3]);
    const short8 b1 = *reinterpret_cast<const short8*>(&Bs[(64 + lane) << 3]);
    const short8 b2 = *reinterpret_cast<const short8*>(&Bs[(128 + lane) << 3]);
    const short8 b3 = *reinterpret_cast<const short8*>(&Bs[(192 + lane) << 3]);
    acc0 = __builtin_amdgcn_mfma_f32_16x16x32_bf16(af, b0, acc0, 0, 0, 0);
    acc1 = __builtin_amdgcn_mfma_f32_16x16x32_bf16(af, b1, acc1, 0, 0, 0);
    acc2 = __builtin_amdgcn_mfma_f32_16x16x32_bf16(af, b2, acc2, 0, 0, 0);
    acc3 = __builtin_amdgcn_mfma_f32_16x16x32_bf16(af, b3, acc3, 0, 0, 0);
    __syncthreads();
  }
  // epilogue: D row = 4*(lane>>4)+i, col = lane&15, per n-tile
  const int q = lane >> 4, cn = lane & 15;
  TC* crow = C + (size_t)(m0 + (w << 4) + (q << 2)) * ldc + n0 + cn;
#pragma unroll
  for (int i = 0; i < 4; ++i) {
    TC* cp = crow + (size_t)i * ldc;
    float v0 = acc0[i], v1 = acc1[i], v2 = acc2[i], v3 = acc3[i];
    if (CADD) { v0 += ldf(cp[0]); v1 += ldf(cp[16]); v2 += ldf(cp[32]); v3 += ldf(cp[48]); }
    stf(cp + 0, v0); stf(cp + 16, v1); stf(cp + 32, v2); stf(cp + 48, v3);
  }
}

// ---------------- row softmax: out = softmax(in) per row ----------------
template <typename TI, typename TO>
__global__ __launch_bounds__(256) void k_softmax_row(const TI* __restrict__ in,
                                                     TO* __restrict__ out, int Lrow) {
  const TI* p = in + (size_t)blockIdx.x * Lrow;
  TO* q = out + (size_t)blockIdx.x * Lrow;
  const int t = threadIdx.x;
  __shared__ float redA[4];
  __shared__ float redB[4];
  float m = -3.4e38f;
  for (int i = t; i < Lrow; i += 256) m = fmaxf(m, ldf(p[i]));
  for (int o = 32; o; o >>= 1) m = fmaxf(m, __shfl_xor(m, o, 64));
  if ((t & 63) == 0) redA[t >> 6] = m;
  __syncthreads();
  m = fmaxf(fmaxf(redA[0], redA[1]), fmaxf(redA[2], redA[3]));
  float s = 0.f;
  for (int i = t; i < Lrow; i += 256) {
    const float e = __expf(ldf(p[i]) - m);
    stf(q + i, e);
    s += e;
  }
  for (int o = 32; o; o >>= 1) s += __shfl_xor(s, o, 64);
  if ((t & 63) == 0) redB[t >> 6] = s;
  __syncthreads();
  s = redB[0] + redB[1] + redB[2] + redB[3];
  const float inv = 1.f / s;
  for (int i = t; i < Lrow; i += 256) stf(q + i, ldf(q[i]) * inv);
}

// -- softmax over s (axis 3) of match[bon][256][128], write transposed [bon][128][256] --
__global__ __launch_bounds__(256) void k_softmax_colT(const float* __restrict__ match,
                                                      u16* __restrict__ qT) {
  const int bon = blockIdx.x, l = blockIdx.y;
  const int t = threadIdx.x;  // s index
  __shared__ float redA[4];
  __shared__ float redB[4];
  const float x = match[((size_t)bon * 256 + t) * 128 + l];
  float m = x;
  for (int o = 32; o; o >>= 1) m = fmaxf(m, __shfl_xor(m, o, 64));
  if ((t & 63) == 0) redA[t >> 6] = m;
  __syncthreads();
  m = fmaxf(fmaxf(redA[0], redA[1]), fmaxf(redA[2], redA[3]));
  const float e = __expf(x - m);
  float s = e;
  for (int o = 32; o; o >>= 1) s += __shfl_xor(s, o, 64);
  if ((t & 63) == 0) redB[t >> 6] = s;
  __syncthreads();
  s = redB[0] + redB[1] + redB[2] + redB[3];
  qT[((size_t)bon * 128 + l) * 256 + t] = f2b(e / s);
}

// ---------------- gate, pool over N, output head, softmax over O ----------------
__global__ __launch_bounds__(256) void k_final(
    const float* __restrict__ s_r, const float* __restrict__ d_r,
    const u16* __restrict__ gw, const u16* __restrict__ gb,
    const u16* __restrict__ ow, const u16* __restrict__ ob,
    void* __restrict__ out, const int* __restrict__ flag) {
  __shared__ float coef[128];
  __shared__ float logits[16];
  const int t = threadIdx.x;
  if (t < 128) {
    float acc = bf2f(gb[0]);
    const float* sp = s_r + (size_t)t * 256;
    const float* dp = d_r + (size_t)t * 256;
    for (int d = 0; d < 256; ++d) acc += bf2f(gw[d]) * sp[d];
    for (int d = 0; d < 256; ++d) acc += bf2f(gw[256 + d]) * dp[d];
    coef[t] = acc;
  }
  __syncthreads();
  if (t < 16) {
    float acc = bf2f(ob[0]);
    for (int d = 0; d < 512; ++d) {
      float mx = -3.4e38f, sm = 0.f;
      for (int n = 0; n < 8; ++n) {
        const int bon = t * 8 + n;
        const float base = (d < 256) ? s_r[(size_t)bon * 256 + d] : d_r[(size_t)bon * 256 + (d - 256)];
        const float v = coef[bon] * base;
        mx = fmaxf(mx, v);
        sm += v;
      }
      acc += bf2f(ow[d]) * mx + bf2f(ow[512 + d]) * (sm * 0.125f);
    }
    logits[t] = acc;
  }
  __syncthreads();
  if (t < 4) {
    const int isf = *flag;
    float m = -3.4e38f;
    for (int o = 0; o < 4; ++o) m = fmaxf(m, logits[t * 4 + o]);
    float e[4], s = 0.f;
    for (int o = 0; o < 4; ++o) { e[o] = __expf(logits[t * 4 + o] - m); s += e[o]; }
    for (int o = 0; o < 4; ++o) {
      const float v = e[o] / s;
      if (isf) ((float*)out)[t * 4 + o] = v;
      else     ((u16*)out)[t * 4 + o] = f2b(v);
    }
  }
}

extern "C" void kernel_launch(void* const* d_in, const int* in_sizes, int n_in,
                              void* d_out, int out_size, void* d_ws, size_t ws_size,
                              hipStream_t stream) {
  (void)in_sizes; (void)n_in; (void)out_size; (void)ws_size;
  const void* statement = d_in[0];
  const void* answer    = d_in[1];
  const void* refs      = d_in[2];
  const void* ctx_wih = d_in[3];
  const void* ctx_whh = d_in[4];
  const void* ctx_bih = d_in[5];
  const void* ctx_bhh = d_in[6];
  const void* sr_wih = d_in[7];
  const void* sr_whh = d_in[8];
  const void* sr_bih = d_in[9];
  const void* sr_bhh = d_in[10];
  const void* dr_wih = d_in[11];
  const void* dr_whh = d_in[12];
  const void* dr_bih = d_in[13];
  const void* dr_bhh = d_in[14];
  const void* gate_w = d_in[15];
  const void* gate_b = d_in[16];
  const void* out_w  = d_in[17];
  const void* out_b  = d_in[18];

  char* ws = (char*)d_ws;
  size_t off = 0;
  auto alloc = [&](size_t bytes) -> void* {
    void* p = ws + off;
    off += (bytes + 255) & ~(size_t)255;
    return p;
  };
  // ---- region A: persistent (~37 MB) ----
  int* FLAG    = (int*)alloc(256);
  u16* CTXWIH  = (u16*)alloc((size_t)768 * 256 * 2);   // bf16 wih (GEMM operand)
  u16* SRWIH   = (u16*)alloc((size_t)768 * 256 * 2);
  u16* DRWIH   = (u16*)alloc((size_t)768 * 512 * 2);
  u32* CTXWHH2 = (u32*)alloc((size_t)128 * 768 * 4);   // fp16 half2, [k8][768][4] u32
  u32* SRWHH2  = (u32*)alloc((size_t)128 * 768 * 4);
  u32* DRWHH2  = (u32*)alloc((size_t)128 * 768 * 4);
  u16* B_CTX_I = (u16*)alloc(768 * 2);
  u16* B_CTX_H = (u16*)alloc(768 * 2);
  u16* B_SR_I  = (u16*)alloc(768 * 2);
  u16* B_SR_H  = (u16*)alloc(768 * 2);
  u16* B_DR_I  = (u16*)alloc(768 * 2);
  u16* B_DR_H  = (u16*)alloc(768 * 2);
  u16* GW = (u16*)alloc(512 * 2);
  u16* GB = (u16*)alloc(2);
  u16* OW = (u16*)alloc(1024 * 2);
  u16* OB = (u16*)alloc(2);
  u16* STMT_H   = (u16*)alloc((size_t)16 * 256 * 256 * 2);   // 2 MB  [bo][s][h]
  u16* DOCS_H   = (u16*)alloc((size_t)128 * 128 * 256 * 2);  // 8 MB  [bon][l][h]
  u16* DOC_READ = (u16*)alloc((size_t)128 * 128 * 256 * 2);  // 8 MB  [bon][l][h]
  u16* ATT      = (u16*)alloc((size_t)128 * 128 * 512 * 2);  // 16 MB [bon][l][2H]
  float* SR_R = (float*)alloc((size_t)128 * 256 * 4);
  float* DR_R = (float*)alloc((size_t)128 * 256 * 4);
  // ---- region B: 66 MB overlay, phase-disjoint lifetimes ----
  const size_t ovl = off;
  u16* REFS_B   = (u16*)(ws + ovl);                           // 8 MB   [phase 1]
  u16* STMT_IN  = (u16*)(ws + ovl + ((size_t)8 << 20));       // 2 MB   [phase 1]
  u16* XG_DOCS  = (u16*)(ws + ovl + ((size_t)16 << 20));      // 24 MB  [phase 1]
  u16* XG_STMT  = (u16*)(ws + ovl + ((size_t)41 << 20));      // 6 MB   [phase 1]
  float* MATCH  = (float*)(ws + ovl);                         // 16 MB  [phase 2]
  u16* P_ROW    = (u16*)(ws + ovl + ((size_t)16 << 20));      // 8 MB   [phase 2]
  u16* MATCH_Q  = (u16*)(ws + ovl + ((size_t)24 << 20));      // 8 MB   [phase 2]
  u16* READ_SUM = (u16*)(ws + ovl + ((size_t)50 << 20));      // 16 MB  [phase 2-3]
  u16* XG_SR    = (u16*)(ws + ovl);                           // 48 MB  [phase 3]
  float* MM     = (float*)(ws + ovl);                         // 64 MB  [phase 4]
  u16* XG_DR    = (u16*)(ws + ovl);                           // 24 MB  [phase 5]

  // 0) dtype detect
  k_detect<<<1, 64, 0, stream>>>(statement, FLAG);

  // 1) conversions / packing
  k_gather_stmt<<<4096, 256, 0, stream>>>(statement, answer, STMT_IN, FLAG);
  k_cvt<<<16384, 256, 0, stream>>>(refs, REFS_B, 4194304, FLAG);
  k_cvt<<<768, 256, 0, stream>>>(ctx_wih, CTXWIH, 196608, FLAG);
  k_cvt<<<768, 256, 0, stream>>>(sr_wih, SRWIH, 196608, FLAG);
  k_cvt<<<1536, 256, 0, stream>>>(dr_wih, DRWIH, 393216, FLAG);
  k_packh<<<384, 256, 0, stream>>>(ctx_whh, CTXWHH2, 98304, FLAG);
  k_packh<<<384, 256, 0, stream>>>(sr_whh, SRWHH2, 98304, FLAG);
  k_packh<<<384, 256, 0, stream>>>(dr_whh, DRWHH2, 98304, FLAG);
  k_cvt<<<3, 256, 0, stream>>>(ctx_bih, B_CTX_I, 768, FLAG);
  k_cvt<<<3, 256, 0, stream>>>(ctx_bhh, B_CTX_H, 768, FLAG);
  k_cvt<<<3, 256, 0, stream>>>(sr_bih, B_SR_I, 768, FLAG);
  k_cvt<<<3, 256, 0, stream>>>(sr_bhh, B_SR_H, 768, FLAG);
  k_cvt<<<3, 256, 0, stream>>>(dr_bih, B_DR_I, 768, FLAG);
  k_cvt<<<3, 256, 0, stream>>>(dr_bhh, B_DR_H, 768, FLAG);
  k_cvt<<<2, 256, 0, stream>>>(gate_w, GW, 512, FLAG);
  k_cvt<<<1, 256, 0, stream>>>(gate_b, GB, 1, FLAG);
  k_cvt<<<4, 256, 0, stream>>>(out_w, OW, 1024, FLAG);
  k_cvt<<<1, 256, 0, stream>>>(out_b, OB, 1, FLAG);

  // 2) ctx input projections: xg = X . wih^T  (M x 768, K=256)
  k_mgemm<true, false, u16, u16, u16><<<dim3(12, 64, 1), 256, 0, stream>>>(
      STMT_IN, 256, 0L, 1, CTXWIH, 256, 0L, 1, XG_STMT, 768, 0L, 256);
  k_mgemm<true, false, u16, u16, u16><<<dim3(12, 256, 1), 256, 0, stream>>>(
      REFS_B, 256, 0L, 1, CTXWIH, 256, 0L, 1, XG_DOCS, 768, 0L, 256);

  // 3) ctx GRUs, fused: stmt (16 seqs, S=1, T=256) + docs (64 blocks, S=2, T=128)
  k_rec<<<80, 768, 0, stream>>>(
      XG_STMT, CTXWHH2, B_CTX_I, B_CTX_H, STMT_H, nullptr, 16, 1, 256,
      XG_DOCS, CTXWHH2, B_CTX_I, B_CTX_H, DOCS_H, nullptr, 2, 128);

  // 4) match[bon][s][l] = stmt[bo] . docs[bon]^T  (M=256,N=128,K=256), fp32 out
  k_mgemm<true, false, u16, u16, float><<<dim3(2, 4, 128), 256, 0, stream>>>(
      STMT_H, 256, 65536L, 8, DOCS_H, 256, 32768L, 1, MATCH, 128, 32768L, 256);

  // 5) softmaxes from raw logits
  k_softmax_colT<<<dim3(128, 128), 256, 0, stream>>>(MATCH, MATCH_Q);
  k_softmax_row<float, u16><<<32768, 256, 0, stream>>>(MATCH, P_ROW, 128);

  // 6) read_sum[bon][s][h] = P_row . docs  (M=256,N=256,K=128), bf16 out
  k_mgemm<false, false, u16, u16, u16><<<dim3(4, 4, 128), 256, 0, stream>>>(
      P_ROW, 128, 32768L, 1, DOCS_H, 256, 32768L, 1, READ_SUM, 256, 65536L, 128);

  // 7) doc_read[bon][l][h] = MATCH_Q . stmt  (M=128,N=256,K=256) — before XG_SR overlay
  k_mgemm<false, false, u16, u16, u16><<<dim3(4, 2, 128), 256, 0, stream>>>(
      MATCH_Q, 256, 32768L, 1, STMT_H, 256, 65536L, 8, DOC_READ, 256, 32768L, 256);

  // 8) sr input projection: XG_SR = READ_SUM . sr_wih^T  (M=32768, K=256)
  k_mgemm<true, false, u16, u16, u16><<<dim3(12, 512, 1), 256, 0, stream>>>(
      READ_SUM, 256, 0L, 1, SRWIH, 256, 0L, 1, XG_SR, 768, 0L, 256);

  // 9) sr GRU (128 seqs, S=2 -> 64 blocks, T=256), max-pooled
  k_rec<<<64, 768, 0, stream>>>(
      XG_SR, SRWHH2, B_SR_I, B_SR_H, nullptr, SR_R, 64, 2, 256,
      nullptr, nullptr, nullptr, nullptr, nullptr, nullptr, 0, 0);

  // 10) mm[bo][nl][m] = docs.docs^T + doc_read.doc_read^T  (M=N=1024,K=256 x2), fp32
  k_mgemm<true, false, u16, u16, float><<<dim3(16, 16, 16), 256, 0, stream>>>(
      DOCS_H, 256, 262144L, 1, DOCS_H, 256, 262144L, 1, MM, 1024, 1048576L, 256);
  k_mgemm<true, true, u16, u16, float><<<dim3(16, 16, 16), 256, 0, stream>>>(
      DOC_READ, 256, 262144L, 1, DOC_READ, 256, 262144L, 1, MM, 1024, 1048576L, 256);

  // 11) softmax over m, in place (fp32)
  k_softmax_row<float, float><<<16384, 256, 0, stream>>>(MM, MM, 1024);

  // 12) att[bon][l][0:256] = P . docs_flat ; [256:512] = P . doc_read_flat (bf16 out)
  k_mgemm<false, false, float, u16, u16><<<dim3(4, 16, 16), 256, 0, stream>>>(
      MM, 1024, 1048576L, 1, DOCS_H, 256, 262144L, 1, ATT, 512, 524288L, 1024);
  k_mgemm<false, false, float, u16, u16><<<dim3(4, 16, 16), 256, 0, stream>>>(
      MM, 1024, 1048576L, 1, DOC_READ, 256, 262144L, 1, ATT + 256, 512, 524288L, 1024);

  // 13) dr input projection: XG_DR = ATT . dr_wih^T  (M=16384, K=512) — MM dead
  k_mgemm<true, false, u16, u16, u16><<<dim3(12, 256, 1), 256, 0, stream>>>(
      ATT, 512, 0L, 1, DRWIH, 512, 0L, 1, XG_DR, 768, 0L, 512);

  // 14) dr GRU (128 seqs, S=2 -> 64 blocks, T=128), max-pooled
  k_rec<<<64, 768, 0, stream>>>(
      XG_DR, DRWHH2, B_DR_I, B_DR_H, nullptr, DR_R, 64, 2, 128,
      nullptr, nullptr, nullptr, nullptr, nullptr, nullptr, 0, 0);

  // 15) gate + pool + head + softmax
  k_final<<<1, 256, 0, stream>>>(SR_R, DR_R, GW, GB, OW, OB, d_out, FLAG);
}

// Round 6
// 2625.153 us; speedup vs baseline: 1.3355x; 1.3355x over previous
//
#include <hip/hip_runtime.h>
#include <hip/hip_bf16.h>
#include <hip/hip_fp16.h>

// SeaReader forward, MI355X. Round 14: S=2 k_rec with manual 4-deep pipelined
// weight stream. r13 showed S=2 correct but latency-bound (VGPR=64, no load
// window: 32 serialized L2 round-trips = 11.5k cyc/step). r8's 4100cyc/step at
// 128 blocks = 86% of aggregate L2 (29.5/34.5 TB/s) => halving traffic via S=2
// only pays with restored MLP. This round: 512-thread geometry (thread = 3
// gate-rows x half-K; 32 LDS h-reads/thread/step, 384 hfma2), weights streamed
// through 4 rotating NAMED register banks issued 4 iterations ahead (first
// banks before the B1 barrier - weights don't depend on h). ~110 VGPR demand,
// no RA fight. Target step ~2100cyc serving 2 seqs (vs r8 4100 serving 1).
// B=4 O=4 L=128 N=8 V=256 H=256; Ls=256; BO=16; BON=128. ws ~103 MB.

typedef unsigned short u16;
typedef unsigned int u32;
typedef __attribute__((ext_vector_type(8))) short short8;
typedef __attribute__((ext_vector_type(4))) float floatx4;

__device__ __forceinline__ float bf2f(u16 v) { return __uint_as_float(((u32)v) << 16); }
__device__ __forceinline__ u16 f2b(float f) {
  u32 u = __float_as_uint(f);
  return (u16)((u + 0x7fffu + ((u >> 16) & 1u)) >> 16);  // RNE; finite inputs only
}
__device__ __forceinline__ float ldf(u16 v) { return bf2f(v); }
__device__ __forceinline__ float ldf(float v) { return v; }
__device__ __forceinline__ void stf(u16* p, float v) { *p = f2b(v); }
__device__ __forceinline__ void stf(float* p, float v) { *p = v; }
__device__ __forceinline__ float ldraw(const void* p, size_t i, int isf) {
  return isf ? ((const float*)p)[i] : bf2f(((const u16*)p)[i]);
}
__device__ __forceinline__ __half2 u2h(u32 v) {
  union { u32 u; __half2 h; } c; c.u = v; return c.h;
}

// ---------------- dtype detection ----------------
__global__ void k_detect(const void* __restrict__ stmt, int* __restrict__ flag) {
  if (threadIdx.x == 0 && blockIdx.x == 0) {
    const float* f = (const float*)stmt;
    int sane = 0;
    for (int i = 0; i < 64; ++i) {
      const float a = fabsf(f[i]);
      if (a > 1e-20f && a < 1e6f) sane++;
    }
    *flag = (sane >= 48) ? 1 : 0;
  }
}

// ---------------- convert raw input to bf16 ----------------
__global__ __launch_bounds__(256) void k_cvt(const void* __restrict__ in, u16* __restrict__ out,
                                             int n, const int* __restrict__ flag) {
  const int isf = *flag;
  const int i = blockIdx.x * 256 + threadIdx.x;
  if (i < n) out[i] = f2b(ldraw(in, i, isf));
}

// ---------------- gather stmt = cat(question, answer) -> bf16 ----------------
__global__ __launch_bounds__(256) void k_gather_stmt(const void* __restrict__ statement,
                                                     const void* __restrict__ answer,
                                                     u16* __restrict__ out,
                                                     const int* __restrict__ flag) {
  const int isf = *flag;
  const int idx = blockIdx.x * 256 + threadIdx.x;  // < 16*256*256
  const int v = idx & 255;
  const int s = (idx >> 8) & 255;
  const int bo = idx >> 16;
  float val;
  if (s < 128) val = ldraw(statement, (size_t)(((bo >> 2) * 128) + s) * 256 + v, isf);
  else         val = ldraw(answer, (size_t)((bo * 128) + (s - 128)) * 256 + v, isf);
  out[idx] = f2b(val);
}

// ---- pack whh [768][256] -> fp16 half2 for the 512-thread k_rec layout ----
// Thread t (pair p=t>>1, K-half kh=t&1) owns rows 3p..3p+2, k in [128kh,128kh+128).
// chunk i (i=ri*16+c) = uint4 at index i*512+t; u32 m within uint4 covers k = kh*128+c*8+2m.
// (verified correct in round 10)
__global__ __launch_bounds__(256) void k_packh(const void* __restrict__ in, u32* __restrict__ out,
                                               int total, const int* __restrict__ flag) {
  const int isf = *flag;
  const int g = blockIdx.x * 256 + threadIdx.x;  // over 98304 u32
  if (g >= total) return;
  const int i = g >> 11;          // chunk 0..47
  const int t = (g >> 2) & 511;   // owning thread
  const int m = g & 3;            // u32 within uint4
  const int row = 3 * (t >> 1) + (i >> 4);
  const int k = (t & 1) * 128 + (i & 15) * 8 + 2 * m;
  const float a = ldraw(in, (size_t)row * 256 + k, isf);
  const float b = ldraw(in, (size_t)row * 256 + k + 1, isf);
  const __half2 h2 = __floats2half2_rn(a, b);
  out[g] = *reinterpret_cast<const u32*>(&h2);
}

// ---------------- recurrent GRU core: S sequences per block, pipelined weight stream ----
// 512 threads (8 waves). Thread (p=t>>1, kh=t&1): rows 3p..3p+2, K-half kh.
// Weights streamed via 4 rotating named register banks (wA/wB/wC per bank = rows 0/1/2),
// issued 4 c-iterations ahead; first 4 banks issued before the B1 barrier.
// h in LDS at half-pos c*16 + kh*8 + j (r11 layout, 0 conflicts measured).
#define LDC(bk, c)                                 \
  wA##bk = wpp[(c) * 512];                         \
  wB##bk = wpp[(16 + (c)) * 512];                  \
  wC##bk = wpp[(32 + (c)) * 512];
#define GCD(bk, c)                                            \
  {                                                           \
    const uint4 hA = hpA[2 * (c)];                            \
    const uint4 hB = hpB[2 * (c)];                            \
    a00 = __hfma2(u2h(wA##bk.x), u2h(hA.x), a00);             \
    a01 = __hfma2(u2h(wA##bk.y), u2h(hA.y), a01);             \
    a00 = __hfma2(u2h(wA##bk.z), u2h(hA.z), a00);             \
    a01 = __hfma2(u2h(wA##bk.w), u2h(hA.w), a01);             \
    c00 = __hfma2(u2h(wA##bk.x), u2h(hB.x), c00);             \
    c01 = __hfma2(u2h(wA##bk.y), u2h(hB.y), c01);             \
    c00 = __hfma2(u2h(wA##bk.z), u2h(hB.z), c00);             \
    c01 = __hfma2(u2h(wA##bk.w), u2h(hB.w), c01);             \
    a10 = __hfma2(u2h(wB##bk.x), u2h(hA.x), a10);             \
    a11 = __hfma2(u2h(wB##bk.y), u2h(hA.y), a11);             \
    a10 = __hfma2(u2h(wB##bk.z), u2h(hA.z), a10);             \
    a11 = __hfma2(u2h(wB##bk.w), u2h(hA.w), a11);             \
    c10 = __hfma2(u2h(wB##bk.x), u2h(hB.x), c10);             \
    c11 = __hfma2(u2h(wB##bk.y), u2h(hB.y), c11);             \
    c10 = __hfma2(u2h(wB##bk.z), u2h(hB.z), c10);             \
    c11 = __hfma2(u2h(wB##bk.w), u2h(hB.w), c11);             \
    a20 = __hfma2(u2h(wC##bk.x), u2h(hA.x), a20);             \
    a21 = __hfma2(u2h(wC##bk.y), u2h(hA.y), a21);             \
    a20 = __hfma2(u2h(wC##bk.z), u2h(hA.z), a20);             \
    a21 = __hfma2(u2h(wC##bk.w), u2h(hA.w), a21);             \
    c20 = __hfma2(u2h(wC##bk.x), u2h(hB.x), c20);             \
    c21 = __hfma2(u2h(wC##bk.y), u2h(hB.y), c21);             \
    c20 = __hfma2(u2h(wC##bk.z), u2h(hB.z), c20);             \
    c21 = __hfma2(u2h(wC##bk.w), u2h(hB.w), c21);             \
  }
#define GCS(bk, c)                                            \
  {                                                           \
    const uint4 hA = hpA[2 * (c)];                            \
    a00 = __hfma2(u2h(wA##bk.x), u2h(hA.x), a00);             \
    a01 = __hfma2(u2h(wA##bk.y), u2h(hA.y), a01);             \
    a00 = __hfma2(u2h(wA##bk.z), u2h(hA.z), a00);             \
    a01 = __hfma2(u2h(wA##bk.w), u2h(hA.w), a01);             \
    a10 = __hfma2(u2h(wB##bk.x), u2h(hA.x), a10);             \
    a11 = __hfma2(u2h(wB##bk.y), u2h(hA.y), a11);             \
    a10 = __hfma2(u2h(wB##bk.z), u2h(hA.z), a10);             \
    a11 = __hfma2(u2h(wB##bk.w), u2h(hA.w), a11);             \
    a20 = __hfma2(u2h(wC##bk.x), u2h(hA.x), a20);             \
    a21 = __hfma2(u2h(wC##bk.y), u2h(hA.y), a21);             \
    a20 = __hfma2(u2h(wC##bk.z), u2h(hA.z), a20);             \
    a21 = __hfma2(u2h(wC##bk.w), u2h(hA.w), a21);             \
  }

__global__ __launch_bounds__(512)
void k_rec(
    const u16* __restrict__ xg0, const u32* __restrict__ whh0,
    const u16* __restrict__ bih0, const u16* __restrict__ bhh0,
    u16* __restrict__ oseq0, float* __restrict__ omax0, int nblk0, int S0, int T0,
    const u16* __restrict__ xg1, const u32* __restrict__ whh1,
    const u16* __restrict__ bih1, const u16* __restrict__ bhh1,
    u16* __restrict__ oseq1, float* __restrict__ omax1, int S1, int T1) {
  __shared__ __align__(16) float hsA_f[256];
  __shared__ __align__(16) float hsB_f[256];
  __shared__ __align__(16) __half hsA_h[256];   // [c][kh][j] interleave
  __shared__ __align__(16) __half hsB_h[256];
  __shared__ __align__(16) float shA[768];
  __shared__ __align__(16) float shB[768];
  const u16 *xg, *bih, *bhh; const u32* whh; u16* oseq; float* omax; int T, S, blk;
  if ((int)blockIdx.x < nblk0) {
    blk = blockIdx.x; xg = xg0; whh = whh0; bih = bih0; bhh = bhh0;
    oseq = oseq0; omax = omax0; T = T0; S = S0;
  } else {
    blk = blockIdx.x - nblk0; xg = xg1; whh = whh1; bih = bih1; bhh = bhh1;
    oseq = oseq1; omax = omax1; T = T1; S = S1;
  }
  const int t = threadIdx.x;        // 0..511
  const int p = t >> 1, kh = t & 1;
  const bool dual = (S == 2);
  const int seqA = blk * S;
  const uint4* wpp = reinterpret_cast<const uint4*>(whh) + t;
  const float bh0 = bf2f(bhh[3 * p]);
  const float bh1 = bf2f(bhh[3 * p + 1]);
  const float bh2 = bf2f(bhh[3 * p + 2]);
  float bir = 0.f, biz = 0.f, bin = 0.f;
  const int e = (t < 256) ? t : (t - 256);
  const int hpos = ((e >> 3) & 15) * 16 + ((e >> 7) << 3) + (e & 7);
  if (t < 256) {
    bir = bf2f(bih[t]); biz = bf2f(bih[t + 256]); bin = bf2f(bih[t + 512]);
    hsA_f[t] = 0.f; hsA_h[hpos] = __float2half(0.f);
  } else if (dual) {
    bir = bf2f(bih[e]); biz = bf2f(bih[e + 256]); bin = bf2f(bih[e + 512]);
    hsB_f[e] = 0.f; hsB_h[hpos] = __float2half(0.f);
  }
  const uint4* hpA = reinterpret_cast<const uint4*>(hsA_h) + kh;
  const uint4* hpB = reinterpret_cast<const uint4*>(hsB_h) + kh;
  float vmax = -3.4e38f;
  const u16* xrowA = xg + (size_t)seqA * T * 768;
  const u16* xrowB = xg + (size_t)(seqA + 1) * T * 768;
  uint4 wA0, wB0, wC0, wA1, wB1, wC1, wA2, wB2, wC2, wA3, wB3, wC3;
  for (int st = 0; st < T; ++st, xrowA += 768, xrowB += 768) {
    float xr = 0.f, xz = 0.f, xn = 0.f;
    if (t < 256) {          // prefetch seq A x-gates
      xr = bf2f(xrowA[t]); xz = bf2f(xrowA[t + 256]); xn = bf2f(xrowA[t + 512]);
    } else if (dual) {      // prefetch seq B x-gates
      xr = bf2f(xrowB[e]); xz = bf2f(xrowB[e + 256]); xn = bf2f(xrowB[e + 512]);
    }
    // issue first 4 weight banks BEFORE the barrier (weights independent of h)
    LDC(0, 0) LDC(1, 1) LDC(2, 2) LDC(3, 3)
    __syncthreads();  // B1: prev-step h updates visible
    const __half2 z2 = __floats2half2_rn(0.f, 0.f);
    __half2 a00 = z2, a01 = z2, a10 = z2, a11 = z2, a20 = z2, a21 = z2;
    __half2 c00 = z2, c01 = z2, c10 = z2, c11 = z2, c20 = z2, c21 = z2;
    if (dual) {
      GCD(0, 0)  LDC(0, 4)
      GCD(1, 1)  LDC(1, 5)
      GCD(2, 2)  LDC(2, 6)
      GCD(3, 3)  LDC(3, 7)
      GCD(0, 4)  LDC(0, 8)
      GCD(1, 5)  LDC(1, 9)
      GCD(2, 6)  LDC(2, 10)
      GCD(3, 7)  LDC(3, 11)
      GCD(0, 8)  LDC(0, 12)
      GCD(1, 9)  LDC(1, 13)
      GCD(2, 10) LDC(2, 14)
      GCD(3, 11) LDC(3, 15)
      GCD(0, 12) GCD(1, 13) GCD(2, 14) GCD(3, 15)
    } else {
      GCS(0, 0)  LDC(0, 4)
      GCS(1, 1)  LDC(1, 5)
      GCS(2, 2)  LDC(2, 6)
      GCS(3, 3)  LDC(3, 7)
      GCS(0, 4)  LDC(0, 8)
      GCS(1, 5)  LDC(1, 9)
      GCS(2, 6)  LDC(2, 10)
      GCS(3, 7)  LDC(3, 11)
      GCS(0, 8)  LDC(0, 12)
      GCS(1, 9)  LDC(1, 13)
      GCS(2, 10) LDC(2, 14)
      GCS(3, 11) LDC(3, 15)
      GCS(0, 12) GCS(1, 13) GCS(2, 14) GCS(3, 15)
    }
    float sA0 = (__low2float(a00) + __high2float(a00)) + (__low2float(a01) + __high2float(a01));
    float sA1 = (__low2float(a10) + __high2float(a10)) + (__low2float(a11) + __high2float(a11));
    float sA2 = (__low2float(a20) + __high2float(a20)) + (__low2float(a21) + __high2float(a21));
    sA0 += __shfl_xor(sA0, 1, 64);
    sA1 += __shfl_xor(sA1, 1, 64);
    sA2 += __shfl_xor(sA2, 1, 64);
    if (!kh) {
      shA[3 * p]     = sA0 + bh0;
      shA[3 * p + 1] = sA1 + bh1;
      shA[3 * p + 2] = sA2 + bh2;
    }
    if (dual) {
      float sB0 = (__low2float(c00) + __high2float(c00)) + (__low2float(c01) + __high2float(c01));
      float sB1 = (__low2float(c10) + __high2float(c10)) + (__low2float(c11) + __high2float(c11));
      float sB2 = (__low2float(c20) + __high2float(c20)) + (__low2float(c21) + __high2float(c21));
      sB0 += __shfl_xor(sB0, 1, 64);
      sB1 += __shfl_xor(sB1, 1, 64);
      sB2 += __shfl_xor(sB2, 1, 64);
      if (!kh) {
        shB[3 * p]     = sB0 + bh0;
        shB[3 * p + 1] = sB1 + bh1;
        shB[3 * p + 2] = sB2 + bh2;
      }
    }
    __syncthreads();  // B2: sh visible; h reads done
    if (t < 256) {
      const float r = 1.f / (1.f + __expf(-(xr + bir + shA[t])));
      const float z = 1.f / (1.f + __expf(-(xz + biz + shA[t + 256])));
      const float n = tanhf(xn + bin + r * shA[t + 512]);
      const float hnew = (1.f - z) * n + z * hsA_f[t];
      hsA_f[t] = hnew;
      hsA_h[hpos] = __float2half(hnew);
      if (oseq) oseq[(size_t)(seqA * T + st) * 256 + t] = f2b(hnew);
      vmax = fmaxf(vmax, hnew);
    } else if (dual) {
      const float r = 1.f / (1.f + __expf(-(xr + bir + shB[e])));
      const float z = 1.f / (1.f + __expf(-(xz + biz + shB[e + 256])));
      const float n = tanhf(xn + bin + r * shB[e + 512]);
      const float hnew = (1.f - z) * n + z * hsB_f[e];
      hsB_f[e] = hnew;
      hsB_h[hpos] = __float2half(hnew);
      if (oseq) oseq[(size_t)((seqA + 1) * T + st) * 256 + e] = f2b(hnew);
      vmax = fmaxf(vmax, hnew);
    }
    // next B1 fences the h updates against next step's reads
  }
  if (omax) {
    if (t < 256) omax[(size_t)seqA * 256 + t] = vmax;
    else if (dual) omax[(size_t)(seqA + 1) * 256 + e] = vmax;
  }
}

// ---------- MFMA bf16 GEMM: C = A * (BT ? B^T : B) (+C), 64x64 tile, 4 waves ----------
// Fragment-order LDS: As[(w*64+lane)*8+j] = A[m0+16w+(lane&15)][k0+8*(lane>>4)+j]
//                     Bs[(nt*64+lane)*8+j] = B[k0+8*(lane>>4)+j][n0+16nt+(lane&15)]
// MFMA layouts per verified notes: A[m=lane&15][k=quad*8+j]; B[k=quad*8+j][n=lane&15];
// D: row=quad*4+reg, col=lane&15.
template <bool BT, bool CADD, typename TA, typename TB, typename TC>
__global__ __launch_bounds__(256) void k_mgemm(
    const TA* __restrict__ Abase, int lda, long strideA, int divA,
    const TB* __restrict__ Bbase, int ldb, long strideB, int divB,
    TC* __restrict__ Cbase, int ldc, long strideC, int K) {
  const int z = blockIdx.z;
  const TA* A = Abase + (size_t)(z / divA) * strideA;
  const TB* Bp = Bbase + (size_t)(z / divB) * strideB;
  TC* C = Cbase + (size_t)z * strideC;
  const int m0 = blockIdx.y << 6, n0 = blockIdx.x << 6;
  __shared__ __align__(16) u16 As[2048];
  __shared__ __align__(16) u16 Bs[2048];
  const int t = threadIdx.x;
  const int lane = t & 63, w = t >> 6;
  floatx4 acc0 = {0.f, 0.f, 0.f, 0.f};
  floatx4 acc1 = {0.f, 0.f, 0.f, 0.f};
  floatx4 acc2 = {0.f, 0.f, 0.f, 0.f};
  floatx4 acc3 = {0.f, 0.f, 0.f, 0.f};
  const int ar = t >> 2;                 // A/BT row (m or n local, 0..63)
  const int ac = (t & 3) << 3;           // k col8
  const int adst = (((ar >> 4) << 6) | (ar & 15) | ((t & 3) << 4)) << 3;
  const int bk = t >> 3;                 // non-BT: k row (0..31)
  const int bn = (t & 7) << 3;           // non-BT: n col8
  for (int k0 = 0; k0 < K; k0 += 32) {
    // stage A[64m][32k] in fragment order
    {
      const TA* ap = A + (size_t)(m0 + ar) * lda + (k0 + ac);
      if constexpr (sizeof(TA) == 2) {
        *reinterpret_cast<uint4*>(&As[adst]) = *reinterpret_cast<const uint4*>(ap);
      } else {
        const float4 f0 = reinterpret_cast<const float4*>(ap)[0];
        const float4 f1 = reinterpret_cast<const float4*>(ap)[1];
        u16* d = &As[adst];
        d[0] = f2b(f0.x); d[1] = f2b(f0.y); d[2] = f2b(f0.z); d[3] = f2b(f0.w);
        d[4] = f2b(f1.x); d[5] = f2b(f1.y); d[6] = f2b(f1.z); d[7] = f2b(f1.w);
      }
    }
    // stage B in fragment order
    if constexpr (BT) {
      const TB* bp = Bp + (size_t)(n0 + ar) * ldb + (k0 + ac);
      *reinterpret_cast<uint4*>(&Bs[adst]) = *reinterpret_cast<const uint4*>(bp);
    } else {
      const TB* bp = Bp + (size_t)(k0 + bk) * ldb + (n0 + bn);
      const uint4 v = *reinterpret_cast<const uint4*>(bp);
      const u16* pv = reinterpret_cast<const u16*>(&v);
#pragma unroll
      for (int j = 0; j < 8; ++j) {
        const int n = bn + j;
        Bs[(((((n >> 4) << 6) | (n & 15) | ((bk >> 3) << 4)) << 3) | (bk & 7))] = pv[j];
      }
    }
    __syncthreads();
    const short8 af = *reinterpret_cast<const short8*>(&As[(w * 64 + lane) << 3]);
    const short8 b0 = *reinterpret_cast<const short8*>(&Bs[(lane) << 3]);
    const short8 b1 = *reinterpret_cast<const short8*>(&Bs[(64 + lane) << 3]);
    const short8 b2 = *reinterpret_cast<const short8*>(&Bs[(128 + lane) << 3]);
    const short8 b3 = *reinterpret_cast<const short8*>(&Bs[(192 + lane) << 3]);
    acc0 = __builtin_amdgcn_mfma_f32_16x16x32_bf16(af, b0, acc0, 0, 0, 0);
    acc1 = __builtin_amdgcn_mfma_f32_16x16x32_bf16(af, b1, acc1, 0, 0, 0);
    acc2 = __builtin_amdgcn_mfma_f32_16x16x32_bf16(af, b2, acc2, 0, 0, 0);
    acc3 = __builtin_amdgcn_mfma_f32_16x16x32_bf16(af, b3, acc3, 0, 0, 0);
    __syncthreads();
  }
  // epilogue: D row = 4*(lane>>4)+i, col = lane&15, per n-tile
  const int q = lane >> 4, cn = lane & 15;
  TC* crow = C + (size_t)(m0 + (w << 4) + (q << 2)) * ldc + n0 + cn;
#pragma unroll
  for (int i = 0; i < 4; ++i) {
    TC* cp = crow + (size_t)i * ldc;
    float v0 = acc0[i], v1 = acc1[i], v2 = acc2[i], v3 = acc3[i];
    if (CADD) { v0 += ldf(cp[0]); v1 += ldf(cp[16]); v2 += ldf(cp[32]); v3 += ldf(cp[48]); }
    stf(cp + 0, v0); stf(cp + 16, v1); stf(cp + 32, v2); stf(cp + 48, v3);
  }
}

// ---------------- row softmax: out = softmax(in) per row ----------------
template <typename TI, typename TO>
__global__ __launch_bounds__(256) void k_softmax_row(const TI* __restrict__ in,
                                                     TO* __restrict__ out, int Lrow) {
  const TI* p = in + (size_t)blockIdx.x * Lrow;
  TO* q = out + (size_t)blockIdx.x * Lrow;
  const int t = threadIdx.x;
  __shared__ float redA[4];
  __shared__ float redB[4];
  float m = -3.4e38f;
  for (int i = t; i < Lrow; i += 256) m = fmaxf(m, ldf(p[i]));
  for (int o = 32; o; o >>= 1) m = fmaxf(m, __shfl_xor(m, o, 64));
  if ((t & 63) == 0) redA[t >> 6] = m;
  __syncthreads();
  m = fmaxf(fmaxf(redA[0], redA[1]), fmaxf(redA[2], redA[3]));
  float s = 0.f;
  for (int i = t; i < Lrow; i += 256) {
    const float e = __expf(ldf(p[i]) - m);
    stf(q + i, e);
    s += e;
  }
  for (int o = 32; o; o >>= 1) s += __shfl_xor(s, o, 64);
  if ((t & 63) == 0) redB[t >> 6] = s;
  __syncthreads();
  s = redB[0] + redB[1] + redB[2] + redB[3];
  const float inv = 1.f / s;
  for (int i = t; i < Lrow; i += 256) stf(q + i, ldf(q[i]) * inv);
}

// -- softmax over s (axis 3) of match[bon][256][128], write transposed [bon][128][256] --
__global__ __launch_bounds__(256) void k_softmax_colT(const float* __restrict__ match,
                                                      u16* __restrict__ qT) {
  const int bon = blockIdx.x, l = blockIdx.y;
  const int t = threadIdx.x;  // s index
  __shared__ float redA[4];
  __shared__ float redB[4];
  const float x = match[((size_t)bon * 256 + t) * 128 + l];
  float m = x;
  for (int o = 32; o; o >>= 1) m = fmaxf(m, __shfl_xor(m, o, 64));
  if ((t & 63) == 0) redA[t >> 6] = m;
  __syncthreads();
  m = fmaxf(fmaxf(redA[0], redA[1]), fmaxf(redA[2], redA[3]));
  const float e = __expf(x - m);
  float s = e;
  for (int o = 32; o; o >>= 1) s += __shfl_xor(s, o, 64);
  if ((t & 63) == 0) redB[t >> 6] = s;
  __syncthreads();
  s = redB[0] + redB[1] + redB[2] + redB[3];
  qT[((size_t)bon * 128 + l) * 256 + t] = f2b(e / s);
}

// ---------------- gate, pool over N, output head, softmax over O ----------------
__global__ __launch_bounds__(256) void k_final(
    const float* __restrict__ s_r, const float* __restrict__ d_r,
    const u16* __restrict__ gw, const u16* __restrict__ gb,
    const u16* __restrict__ ow, const u16* __restrict__ ob,
    void* __restrict__ out, const int* __restrict__ flag) {
  __shared__ float coef[128];
  __shared__ float logits[16];
  const int t = threadIdx.x;
  if (t < 128) {
    float acc = bf2f(gb[0]);
    const float* sp = s_r + (size_t)t * 256;
    const float* dp = d_r + (size_t)t * 256;
    for (int d = 0; d < 256; ++d) acc += bf2f(gw[d]) * sp[d];
    for (int d = 0; d < 256; ++d) acc += bf2f(gw[256 + d]) * dp[d];
    coef[t] = acc;
  }
  __syncthreads();
  if (t < 16) {
    float acc = bf2f(ob[0]);
    for (int d = 0; d < 512; ++d) {
      float mx = -3.4e38f, sm = 0.f;
      for (int n = 0; n < 8; ++n) {
        const int bon = t * 8 + n;
        const float base = (d < 256) ? s_r[(size_t)bon * 256 + d] : d_r[(size_t)bon * 256 + (d - 256)];
        const float v = coef[bon] * base;
        mx = fmaxf(mx, v);
        sm += v;
      }
      acc += bf2f(ow[d]) * mx + bf2f(ow[512 + d]) * (sm * 0.125f);
    }
    logits[t] = acc;
  }
  __syncthreads();
  if (t < 4) {
    const int isf = *flag;
    float m = -3.4e38f;
    for (int o = 0; o < 4; ++o) m = fmaxf(m, logits[t * 4 + o]);
    float e[4], s = 0.f;
    for (int o = 0; o < 4; ++o) { e[o] = __expf(logits[t * 4 + o] - m); s += e[o]; }
    for (int o = 0; o < 4; ++o) {
      const float v = e[o] / s;
      if (isf) ((float*)out)[t * 4 + o] = v;
      else     ((u16*)out)[t * 4 + o] = f2b(v);
    }
  }
}

extern "C" void kernel_launch(void* const* d_in, const int* in_sizes, int n_in,
                              void* d_out, int out_size, void* d_ws, size_t ws_size,
                              hipStream_t stream) {
  (void)in_sizes; (void)n_in; (void)out_size; (void)ws_size;
  const void* statement = d_in[0];
  const void* answer    = d_in[1];
  const void* refs      = d_in[2];
  const void* ctx_wih = d_in[3];
  const void* ctx_whh = d_in[4];
  const void* ctx_bih = d_in[5];
  const void* ctx_bhh = d_in[6];
  const void* sr_wih = d_in[7];
  const void* sr_whh = d_in[8];
  const void* sr_bih = d_in[9];
  const void* sr_bhh = d_in[10];
  const void* dr_wih = d_in[11];
  const void* dr_whh = d_in[12];
  const void* dr_bih = d_in[13];
  const void* dr_bhh = d_in[14];
  const void* gate_w = d_in[15];
  const void* gate_b = d_in[16];
  const void* out_w  = d_in[17];
  const void* out_b  = d_in[18];

  char* ws = (char*)d_ws;
  size_t off = 0;
  auto alloc = [&](size_t bytes) -> void* {
    void* p = ws + off;
    off += (bytes + 255) & ~(size_t)255;
    return p;
  };
  // ---- region A: persistent (~37 MB) ----
  int* FLAG    = (int*)alloc(256);
  u16* CTXWIH  = (u16*)alloc((size_t)768 * 256 * 2);   // bf16 wih (GEMM operand)
  u16* SRWIH   = (u16*)alloc((size_t)768 * 256 * 2);
  u16* DRWIH   = (u16*)alloc((size_t)768 * 512 * 2);
  u32* CTXWHH2 = (u32*)alloc((size_t)128 * 768 * 4);   // fp16 half2, k_rec-thread layout
  u32* SRWHH2  = (u32*)alloc((size_t)128 * 768 * 4);
  u32* DRWHH2  = (u32*)alloc((size_t)128 * 768 * 4);
  u16* B_CTX_I = (u16*)alloc(768 * 2);
  u16* B_CTX_H = (u16*)alloc(768 * 2);
  u16* B_SR_I  = (u16*)alloc(768 * 2);
  u16* B_SR_H  = (u16*)alloc(768 * 2);
  u16* B_DR_I  = (u16*)alloc(768 * 2);
  u16* B_DR_H  = (u16*)alloc(768 * 2);
  u16* GW = (u16*)alloc(512 * 2);
  u16* GB = (u16*)alloc(2);
  u16* OW = (u16*)alloc(1024 * 2);
  u16* OB = (u16*)alloc(2);
  u16* STMT_H   = (u16*)alloc((size_t)16 * 256 * 256 * 2);   // 2 MB  [bo][s][h]
  u16* DOCS_H   = (u16*)alloc((size_t)128 * 128 * 256 * 2);  // 8 MB  [bon][l][h]
  u16* DOC_READ = (u16*)alloc((size_t)128 * 128 * 256 * 2);  // 8 MB  [bon][l][h]
  u16* ATT      = (u16*)alloc((size_t)128 * 128 * 512 * 2);  // 16 MB [bon][l][2H]
  float* SR_R = (float*)alloc((size_t)128 * 256 * 4);
  float* DR_R = (float*)alloc((size_t)128 * 256 * 4);
  // ---- region B: 66 MB overlay, phase-disjoint lifetimes ----
  const size_t ovl = off;
  u16* REFS_B   = (u16*)(ws + ovl);                           // 8 MB   [phase 1]
  u16* STMT_IN  = (u16*)(ws + ovl + ((size_t)8 << 20));       // 2 MB   [phase 1]
  u16* XG_DOCS  = (u16*)(ws + ovl + ((size_t)16 << 20));      // 24 MB  [phase 1]
  u16* XG_STMT  = (u16*)(ws + ovl + ((size_t)41 << 20));      // 6 MB   [phase 1]
  float* MATCH  = (float*)(ws + ovl);                         // 16 MB  [phase 2]
  u16* P_ROW    = (u16*)(ws + ovl + ((size_t)16 << 20));      // 8 MB   [phase 2]
  u16* MATCH_Q  = (u16*)(ws + ovl + ((size_t)24 << 20));      // 8 MB   [phase 2]
  u16* READ_SUM = (u16*)(ws + ovl + ((size_t)50 << 20));      // 16 MB  [phase 2-3]
  u16* XG_SR    = (u16*)(ws + ovl);                           // 48 MB  [phase 3]
  float* MM     = (float*)(ws + ovl);                         // 64 MB  [phase 4]
  u16* XG_DR    = (u16*)(ws + ovl);                           // 24 MB  [phase 5]

  // 0) dtype detect
  k_detect<<<1, 64, 0, stream>>>(statement, FLAG);

  // 1) conversions / packing
  k_gather_stmt<<<4096, 256, 0, stream>>>(statement, answer, STMT_IN, FLAG);
  k_cvt<<<16384, 256, 0, stream>>>(refs, REFS_B, 4194304, FLAG);
  k_cvt<<<768, 256, 0, stream>>>(ctx_wih, CTXWIH, 196608, FLAG);
  k_cvt<<<768, 256, 0, stream>>>(sr_wih, SRWIH, 196608, FLAG);
  k_cvt<<<1536, 256, 0, stream>>>(dr_wih, DRWIH, 393216, FLAG);
  k_packh<<<384, 256, 0, stream>>>(ctx_whh, CTXWHH2, 98304, FLAG);
  k_packh<<<384, 256, 0, stream>>>(sr_whh, SRWHH2, 98304, FLAG);
  k_packh<<<384, 256, 0, stream>>>(dr_whh, DRWHH2, 98304, FLAG);
  k_cvt<<<3, 256, 0, stream>>>(ctx_bih, B_CTX_I, 768, FLAG);
  k_cvt<<<3, 256, 0, stream>>>(ctx_bhh, B_CTX_H, 768, FLAG);
  k_cvt<<<3, 256, 0, stream>>>(sr_bih, B_SR_I, 768, FLAG);
  k_cvt<<<3, 256, 0, stream>>>(sr_bhh, B_SR_H, 768, FLAG);
  k_cvt<<<3, 256, 0, stream>>>(dr_bih, B_DR_I, 768, FLAG);
  k_cvt<<<3, 256, 0, stream>>>(dr_bhh, B_DR_H, 768, FLAG);
  k_cvt<<<2, 256, 0, stream>>>(gate_w, GW, 512, FLAG);
  k_cvt<<<1, 256, 0, stream>>>(gate_b, GB, 1, FLAG);
  k_cvt<<<4, 256, 0, stream>>>(out_w, OW, 1024, FLAG);
  k_cvt<<<1, 256, 0, stream>>>(out_b, OB, 1, FLAG);

  // 2) ctx input projections: xg = X . wih^T  (M x 768, K=256)
  k_mgemm<true, false, u16, u16, u16><<<dim3(12, 64, 1), 256, 0, stream>>>(
      STMT_IN, 256, 0L, 1, CTXWIH, 256, 0L, 1, XG_STMT, 768, 0L, 256);
  k_mgemm<true, false, u16, u16, u16><<<dim3(12, 256, 1), 256, 0, stream>>>(
      REFS_B, 256, 0L, 1, CTXWIH, 256, 0L, 1, XG_DOCS, 768, 0L, 256);

  // 3) ctx GRUs, fused: stmt (16 seqs, S=1, T=256) + docs (64 blocks, S=2, T=128)
  k_rec<<<80, 512, 0, stream>>>(
      XG_STMT, CTXWHH2, B_CTX_I, B_CTX_H, STMT_H, nullptr, 16, 1, 256,
      XG_DOCS, CTXWHH2, B_CTX_I, B_CTX_H, DOCS_H, nullptr, 2, 128);

  // 4) match[bon][s][l] = stmt[bo] . docs[bon]^T  (M=256,N=128,K=256), fp32 out
  k_mgemm<true, false, u16, u16, float><<<dim3(2, 4, 128), 256, 0, stream>>>(
      STMT_H, 256, 65536L, 8, DOCS_H, 256, 32768L, 1, MATCH, 128, 32768L, 256);

  // 5) softmaxes from raw logits
  k_softmax_colT<<<dim3(128, 128), 256, 0, stream>>>(MATCH, MATCH_Q);
  k_softmax_row<float, u16><<<32768, 256, 0, stream>>>(MATCH, P_ROW, 128);

  // 6) read_sum[bon][s][h] = P_row . docs  (M=256,N=256,K=128), bf16 out
  k_mgemm<false, false, u16, u16, u16><<<dim3(4, 4, 128), 256, 0, stream>>>(
      P_ROW, 128, 32768L, 1, DOCS_H, 256, 32768L, 1, READ_SUM, 256, 65536L, 128);

  // 7) doc_read[bon][l][h] = MATCH_Q . stmt  (M=128,N=256,K=256) — before XG_SR overlay
  k_mgemm<false, false, u16, u16, u16><<<dim3(4, 2, 128), 256, 0, stream>>>(
      MATCH_Q, 256, 32768L, 1, STMT_H, 256, 65536L, 8, DOC_READ, 256, 32768L, 256);

  // 8) sr input projection: XG_SR = READ_SUM . sr_wih^T  (M=32768, K=256)
  k_mgemm<true, false, u16, u16, u16><<<dim3(12, 512, 1), 256, 0, stream>>>(
      READ_SUM, 256, 0L, 1, SRWIH, 256, 0L, 1, XG_SR, 768, 0L, 256);

  // 9) sr GRU (128 seqs, S=2 -> 64 blocks, T=256), max-pooled
  k_rec<<<64, 512, 0, stream>>>(
      XG_SR, SRWHH2, B_SR_I, B_SR_H, nullptr, SR_R, 64, 2, 256,
      nullptr, nullptr, nullptr, nullptr, nullptr, nullptr, 0, 0);

  // 10) mm[bo][nl][m] = docs.docs^T + doc_read.doc_read^T  (M=N=1024,K=256 x2), fp32
  k_mgemm<true, false, u16, u16, float><<<dim3(16, 16, 16), 256, 0, stream>>>(
      DOCS_H, 256, 262144L, 1, DOCS_H, 256, 262144L, 1, MM, 1024, 1048576L, 256);
  k_mgemm<true, true, u16, u16, float><<<dim3(16, 16, 16), 256, 0, stream>>>(
      DOC_READ, 256, 262144L, 1, DOC_READ, 256, 262144L, 1, MM, 1024, 1048576L, 256);

  // 11) softmax over m, in place (fp32)
  k_softmax_row<float, float><<<16384, 256, 0, stream>>>(MM, MM, 1024);

  // 12) att[bon][l][0:256] = P . docs_flat ; [256:512] = P . doc_read_flat (bf16 out)
  k_mgemm<false, false, float, u16, u16><<<dim3(4, 16, 16), 256, 0, stream>>>(
      MM, 1024, 1048576L, 1, DOCS_H, 256, 262144L, 1, ATT, 512, 524288L, 1024);
  k_mgemm<false, false, float, u16, u16><<<dim3(4, 16, 16), 256, 0, stream>>>(
      MM, 1024, 1048576L, 1, DOC_READ, 256, 262144L, 1, ATT + 256, 512, 524288L, 1024);

  // 13) dr input projection: XG_DR = ATT . dr_wih^T  (M=16384, K=512) — MM dead
  k_mgemm<true, false, u16, u16, u16><<<dim3(12, 256, 1), 256, 0, stream>>>(
      ATT, 512, 0L, 1, DRWIH, 512, 0L, 1, XG_DR, 768, 0L, 512);

  // 14) dr GRU (128 seqs, S=2 -> 64 blocks, T=128), max-pooled
  k_rec<<<64, 512, 0, stream>>>(
      XG_DR, DRWHH2, B_DR_I, B_DR_H, nullptr, DR_R, 64, 2, 128,
      nullptr, nullptr, nullptr, nullptr, nullptr, nullptr, 0, 0);

  // 15) gate + pool + head + softmax
  k_final<<<1, 256, 0, stream>>>(SR_R, DR_R, GW, GB, OW, OB, d_out, FLAG);
}

// Round 7
// 1757.966 us; speedup vs baseline: 1.9944x; 1.4933x over previous
//
#include <hip/hip_runtime.h>
#include <hip/hip_bf16.h>
#include <hip/hip_fp16.h>

// SeaReader forward, MI355X. Round 15: k_rec hybrid LDS-resident weights.
// History: r8 baseline (1713us) streams whh 393KB/step/block from L2 at the
// MLP-limited ~96 B/cyc/CU (4100cyc/step). r9-r12 (register residency) lost to
// the RA four ways; r13/r14 (S-batching) showed per-block stream time is
// invariant and restructuring breaks the compiler's good schedule. This round
// keeps the EXACT r8 structure (768 thr, 12 waves, STEPW pattern, S=1, same
// grids) and moves k-chunks 0..11 (cols 0..95, 147KB fp16) into LDS once per
// block; per step they're read via ds_read_b128 (own-slot, conflict-free, no
// barrier needed) while chunks 12..31 stream as before. Streamed bytes/step:
// 393->245KB => step ~2600-2800cyc. LDS 152KB -> 1 block/CU as before.
// B=4 O=4 L=128 N=8 V=256 H=256; Ls=256; BO=16; BON=128. ws ~103 MB.

typedef unsigned short u16;
typedef unsigned int u32;
typedef __attribute__((ext_vector_type(8))) short short8;
typedef __attribute__((ext_vector_type(4))) float floatx4;

__device__ __forceinline__ float bf2f(u16 v) { return __uint_as_float(((u32)v) << 16); }
__device__ __forceinline__ u16 f2b(float f) {
  u32 u = __float_as_uint(f);
  return (u16)((u + 0x7fffu + ((u >> 16) & 1u)) >> 16);  // RNE; finite inputs only
}
__device__ __forceinline__ float ldf(u16 v) { return bf2f(v); }
__device__ __forceinline__ float ldf(float v) { return v; }
__device__ __forceinline__ void stf(u16* p, float v) { *p = f2b(v); }
__device__ __forceinline__ void stf(float* p, float v) { *p = v; }
__device__ __forceinline__ float ldraw(const void* p, size_t i, int isf) {
  return isf ? ((const float*)p)[i] : bf2f(((const u16*)p)[i]);
}
__device__ __forceinline__ __half2 u2h(u32 v) {
  union { u32 u; __half2 h; } c; c.u = v; return c.h;
}

// ---------------- dtype detection ----------------
__global__ void k_detect(const void* __restrict__ stmt, int* __restrict__ flag) {
  if (threadIdx.x == 0 && blockIdx.x == 0) {
    const float* f = (const float*)stmt;
    int sane = 0;
    for (int i = 0; i < 64; ++i) {
      const float a = fabsf(f[i]);
      if (a > 1e-20f && a < 1e6f) sane++;
    }
    *flag = (sane >= 48) ? 1 : 0;
  }
}

// ---------------- convert raw input to bf16 ----------------
__global__ __launch_bounds__(256) void k_cvt(const void* __restrict__ in, u16* __restrict__ out,
                                             int n, const int* __restrict__ flag) {
  const int isf = *flag;
  const int i = blockIdx.x * 256 + threadIdx.x;
  if (i < n) out[i] = f2b(ldraw(in, i, isf));
}

// ---------------- gather stmt = cat(question, answer) -> bf16 ----------------
__global__ __launch_bounds__(256) void k_gather_stmt(const void* __restrict__ statement,
                                                     const void* __restrict__ answer,
                                                     u16* __restrict__ out,
                                                     const int* __restrict__ flag) {
  const int isf = *flag;
  const int idx = blockIdx.x * 256 + threadIdx.x;  // < 16*256*256
  const int v = idx & 255;
  const int s = (idx >> 8) & 255;
  const int bo = idx >> 16;
  float val;
  if (s < 128) val = ldraw(statement, (size_t)(((bo >> 2) * 128) + s) * 256 + v, isf);
  else         val = ldraw(answer, (size_t)((bo * 128) + (s - 128)) * 256 + v, isf);
  out[idx] = f2b(val);
}

// ---- pack whh [768][256] -> fp16 half2 in [k8][768][4] u32 (thread-contiguous uint4) ----
// Gate-row r's chunk i (covering h[8i..8i+8)) = uint4 at index i*768 + r.
__global__ __launch_bounds__(256) void k_packh(const void* __restrict__ in, u32* __restrict__ out,
                                               int total, const int* __restrict__ flag) {
  const int isf = *flag;
  const int idx = blockIdx.x * 256 + threadIdx.x;  // over 768*128 (row, k2)
  if (idx >= total) return;
  const int r = idx % 768;
  const int k2 = idx / 768;
  const float a = ldraw(in, (size_t)r * 256 + 2 * k2, isf);
  const float b = ldraw(in, (size_t)r * 256 + 2 * k2 + 1, isf);
  const __half2 h2 = __floats2half2_rn(a, b);
  out[(((size_t)(k2 >> 2) * 768) + r) * 4 + (k2 & 3)] = *reinterpret_cast<const u32*>(&h2);
}

// ---------------- recurrent GRU core: xg precomputed; hybrid LDS/stream weights ----------------
// One block per sequence, 768 threads = gate-rows. Dual-job (two independent GRUs/launch).
// k-chunks 0..11 (cols 0..95, 147KB) preloaded into LDS per block (each thread writes and
// reads only its own 12 slots -> no barrier, no conflicts); chunks 12..31 streamed from L2
// per step exactly as the r8-proven pattern (compiler schedules ~96 B/cyc/CU).
#define NLDS 12
#define STEPG(i)                                                             \
  {                                                                          \
    const uint4 wv = wp[(i) * 768];                                          \
    const uint4 hv = *reinterpret_cast<const uint4*>(&hs_h[(i) * 8]);        \
    a0 = __hfma2(u2h(wv.x), u2h(hv.x), a0);                                  \
    a1 = __hfma2(u2h(wv.y), u2h(hv.y), a1);                                  \
    a2 = __hfma2(u2h(wv.z), u2h(hv.z), a2);                                  \
    a3 = __hfma2(u2h(wv.w), u2h(hv.w), a3);                                  \
  }
#define STEPL(i)                                                             \
  {                                                                          \
    const uint4 wv = Wl[(i) * 768 + t];                                      \
    const uint4 hv = *reinterpret_cast<const uint4*>(&hs_h[(i) * 8]);        \
    a0 = __hfma2(u2h(wv.x), u2h(hv.x), a0);                                  \
    a1 = __hfma2(u2h(wv.y), u2h(hv.y), a1);                                  \
    a2 = __hfma2(u2h(wv.z), u2h(hv.z), a2);                                  \
    a3 = __hfma2(u2h(wv.w), u2h(hv.w), a3);                                  \
  }

__global__ __attribute__((amdgpu_flat_work_group_size(768, 768), amdgpu_waves_per_eu(3, 3)))
void k_rec(
    const u16* __restrict__ xg0, const u32* __restrict__ whh0,
    const u16* __restrict__ bih0, const u16* __restrict__ bhh0,
    u16* __restrict__ oseq0, float* __restrict__ omax0, int nseq0, int T0,
    const u16* __restrict__ xg1, const u32* __restrict__ whh1,
    const u16* __restrict__ bih1, const u16* __restrict__ bhh1,
    u16* __restrict__ oseq1, float* __restrict__ omax1, int T1) {
  __shared__ __align__(16) uint4 Wl[NLDS * 768];   // 147,456 B resident weights
  __shared__ __align__(16) float hs_f[256];
  __shared__ __align__(16) __half hs_h[256];
  __shared__ __align__(16) float sh[768];
  const u16 *xg, *bih, *bhh; const u32* whh; u16* oseq; float* omax; int T, seq;
  if ((int)blockIdx.x < nseq0) {
    seq = blockIdx.x; xg = xg0; whh = whh0; bih = bih0; bhh = bhh0;
    oseq = oseq0; omax = omax0; T = T0;
  } else {
    seq = blockIdx.x - nseq0; xg = xg1; whh = whh1; bih = bih1; bhh = bhh1;
    oseq = oseq1; omax = omax1; T = T1;
  }
  const int t = threadIdx.x;
  const uint4* wp = reinterpret_cast<const uint4*>(whh) + t;
  // one-time preload of k-chunks 0..11 into LDS (own-slot: no barrier needed)
#pragma unroll
  for (int i = 0; i < NLDS; ++i) Wl[i * 768 + t] = wp[i * 768];
  const float bh = bf2f(bhh[t]);
  float bir = 0.f, biz = 0.f, bin = 0.f;
  if (t < 256) {
    bir = bf2f(bih[t]); biz = bf2f(bih[t + 256]); bin = bf2f(bih[t + 512]);
    hs_f[t] = 0.f;
    hs_h[t] = __float2half(0.f);
  }
  float vmax = -3.4e38f;
  const u16* xrow = xg + (size_t)seq * T * 768;
  for (int st = 0; st < T; ++st, xrow += 768) {
    float xr = 0.f, xz = 0.f, xn = 0.f;
    if (t < 256) {  // prefetch this step's x-gates; latency hidden under hh-loop
      xr = bf2f(xrow[t]); xz = bf2f(xrow[t + 256]); xn = bf2f(xrow[t + 512]);
    }
    __syncthreads();  // B1: prev-step h updates visible
    __half2 a0 = __floats2half2_rn(0.f, 0.f), a1 = a0, a2 = a0, a3 = a0;
    // streamed chunks first (loads issue early, latency hidden under LDS chunks)
    STEPG(12) STEPG(13) STEPG(14) STEPG(15) STEPG(16) STEPG(17) STEPG(18) STEPG(19)
    STEPG(20) STEPG(21) STEPG(22) STEPG(23) STEPG(24) STEPG(25) STEPG(26) STEPG(27)
    STEPG(28) STEPG(29) STEPG(30) STEPG(31)
    // LDS-resident chunks
    STEPL(0)  STEPL(1)  STEPL(2)  STEPL(3)  STEPL(4)  STEPL(5)  STEPL(6)  STEPL(7)
    STEPL(8)  STEPL(9)  STEPL(10) STEPL(11)
    const float ah = (__low2float(a0) + __high2float(a0)) + (__low2float(a1) + __high2float(a1))
                   + (__low2float(a2) + __high2float(a2)) + (__low2float(a3) + __high2float(a3));
    sh[t] = ah + bh;
    __syncthreads();  // B2: sh visible; hs_h reads done
    if (t < 256) {
      const float r = 1.f / (1.f + __expf(-(xr + bir + sh[t])));
      const float z = 1.f / (1.f + __expf(-(xz + biz + sh[t + 256])));
      const float n = tanhf(xn + bin + r * sh[t + 512]);
      const float hnew = (1.f - z) * n + z * hs_f[t];
      hs_f[t] = hnew;
      hs_h[t] = __float2half(hnew);
      if (oseq) oseq[(size_t)(seq * T + st) * 256 + t] = f2b(hnew);
      vmax = fmaxf(vmax, hnew);
    }
    // next B1 fences the h update against next step's reads
  }
  if (omax && t < 256) omax[(size_t)seq * 256 + t] = vmax;
}

// ---------- MFMA bf16 GEMM: C = A * (BT ? B^T : B) (+C), 64x64 tile, 4 waves ----------
// Fragment-order LDS: As[(w*64+lane)*8+j] = A[m0+16w+(lane&15)][k0+8*(lane>>4)+j]
//                     Bs[(nt*64+lane)*8+j] = B[k0+8*(lane>>4)+j][n0+16nt+(lane&15)]
// MFMA layouts per verified notes: A[m=lane&15][k=quad*8+j]; B[k=quad*8+j][n=lane&15];
// D: row=quad*4+reg, col=lane&15.
template <bool BT, bool CADD, typename TA, typename TB, typename TC>
__global__ __launch_bounds__(256) void k_mgemm(
    const TA* __restrict__ Abase, int lda, long strideA, int divA,
    const TB* __restrict__ Bbase, int ldb, long strideB, int divB,
    TC* __restrict__ Cbase, int ldc, long strideC, int K) {
  const int z = blockIdx.z;
  const TA* A = Abase + (size_t)(z / divA) * strideA;
  const TB* Bp = Bbase + (size_t)(z / divB) * strideB;
  TC* C = Cbase + (size_t)z * strideC;
  const int m0 = blockIdx.y << 6, n0 = blockIdx.x << 6;
  __shared__ __align__(16) u16 As[2048];
  __shared__ __align__(16) u16 Bs[2048];
  const int t = threadIdx.x;
  const int lane = t & 63, w = t >> 6;
  floatx4 acc0 = {0.f, 0.f, 0.f, 0.f};
  floatx4 acc1 = {0.f, 0.f, 0.f, 0.f};
  floatx4 acc2 = {0.f, 0.f, 0.f, 0.f};
  floatx4 acc3 = {0.f, 0.f, 0.f, 0.f};
  const int ar = t >> 2;                 // A/BT row (m or n local, 0..63)
  const int ac = (t & 3) << 3;           // k col8
  const int adst = (((ar >> 4) << 6) | (ar & 15) | ((t & 3) << 4)) << 3;
  const int bk = t >> 3;                 // non-BT: k row (0..31)
  const int bn = (t & 7) << 3;           // non-BT: n col8
  for (int k0 = 0; k0 < K; k0 += 32) {
    // stage A[64m][32k] in fragment order
    {
      const TA* ap = A + (size_t)(m0 + ar) * lda + (k0 + ac);
      if constexpr (sizeof(TA) == 2) {
        *reinterpret_cast<uint4*>(&As[adst]) = *reinterpret_cast<const uint4*>(ap);
      } else {
        const float4 f0 = reinterpret_cast<const float4*>(ap)[0];
        const float4 f1 = reinterpret_cast<const float4*>(ap)[1];
        u16* d = &As[adst];
        d[0] = f2b(f0.x); d[1] = f2b(f0.y); d[2] = f2b(f0.z); d[3] = f2b(f0.w);
        d[4] = f2b(f1.x); d[5] = f2b(f1.y); d[6] = f2b(f1.z); d[7] = f2b(f1.w);
      }
    }
    // stage B in fragment order
    if constexpr (BT) {
      const TB* bp = Bp + (size_t)(n0 + ar) * ldb + (k0 + ac);
      *reinterpret_cast<uint4*>(&Bs[adst]) = *reinterpret_cast<const uint4*>(bp);
    } else {
      const TB* bp = Bp + (size_t)(k0 + bk) * ldb + (n0 + bn);
      const uint4 v = *reinterpret_cast<const uint4*>(bp);
      const u16* pv = reinterpret_cast<const u16*>(&v);
#pragma unroll
      for (int j = 0; j < 8; ++j) {
        const int n = bn + j;
        Bs[(((((n >> 4) << 6) | (n & 15) | ((bk >> 3) << 4)) << 3) | (bk & 7))] = pv[j];
      }
    }
    __syncthreads();
    const short8 af = *reinterpret_cast<const short8*>(&As[(w * 64 + lane) << 3]);
    const short8 b0 = *reinterpret_cast<const short8*>(&Bs[(lane) << 3]);
    const short8 b1 = *reinterpret_cast<const short8*>(&Bs[(64 + lane) << 3]);
    const short8 b2 = *reinterpret_cast<const short8*>(&Bs[(128 + lane) << 3]);
    const short8 b3 = *reinterpret_cast<const short8*>(&Bs[(192 + lane) << 3]);
    acc0 = __builtin_amdgcn_mfma_f32_16x16x32_bf16(af, b0, acc0, 0, 0, 0);
    acc1 = __builtin_amdgcn_mfma_f32_16x16x32_bf16(af, b1, acc1, 0, 0, 0);
    acc2 = __builtin_amdgcn_mfma_f32_16x16x32_bf16(af, b2, acc2, 0, 0, 0);
    acc3 = __builtin_amdgcn_mfma_f32_16x16x32_bf16(af, b3, acc3, 0, 0, 0);
    __syncthreads();
  }
  // epilogue: D row = 4*(lane>>4)+i, col = lane&15, per n-tile
  const int q = lane >> 4, cn = lane & 15;
  TC* crow = C + (size_t)(m0 + (w << 4) + (q << 2)) * ldc + n0 + cn;
#pragma unroll
  for (int i = 0; i < 4; ++i) {
    TC* cp = crow + (size_t)i * ldc;
    float v0 = acc0[i], v1 = acc1[i], v2 = acc2[i], v3 = acc3[i];
    if (CADD) { v0 += ldf(cp[0]); v1 += ldf(cp[16]); v2 += ldf(cp[32]); v3 += ldf(cp[48]); }
    stf(cp + 0, v0); stf(cp + 16, v1); stf(cp + 32, v2); stf(cp + 48, v3);
  }
}

// ---------------- row softmax: out = softmax(in) per row ----------------
template <typename TI, typename TO>
__global__ __launch_bounds__(256) void k_softmax_row(const TI* __restrict__ in,
                                                     TO* __restrict__ out, int Lrow) {
  const TI* p = in + (size_t)blockIdx.x * Lrow;
  TO* q = out + (size_t)blockIdx.x * Lrow;
  const int t = threadIdx.x;
  __shared__ float redA[4];
  __shared__ float redB[4];
  float m = -3.4e38f;
  for (int i = t; i < Lrow; i += 256) m = fmaxf(m, ldf(p[i]));
  for (int o = 32; o; o >>= 1) m = fmaxf(m, __shfl_xor(m, o, 64));
  if ((t & 63) == 0) redA[t >> 6] = m;
  __syncthreads();
  m = fmaxf(fmaxf(redA[0], redA[1]), fmaxf(redA[2], redA[3]));
  float s = 0.f;
  for (int i = t; i < Lrow; i += 256) {
    const float e = __expf(ldf(p[i]) - m);
    stf(q + i, e);
    s += e;
  }
  for (int o = 32; o; o >>= 1) s += __shfl_xor(s, o, 64);
  if ((t & 63) == 0) redB[t >> 6] = s;
  __syncthreads();
  s = redB[0] + redB[1] + redB[2] + redB[3];
  const float inv = 1.f / s;
  for (int i = t; i < Lrow; i += 256) stf(q + i, ldf(q[i]) * inv);
}

// -- softmax over s (axis 3) of match[bon][256][128], write transposed [bon][128][256] --
__global__ __launch_bounds__(256) void k_softmax_colT(const float* __restrict__ match,
                                                      u16* __restrict__ qT) {
  const int bon = blockIdx.x, l = blockIdx.y;
  const int t = threadIdx.x;  // s index
  __shared__ float redA[4];
  __shared__ float redB[4];
  const float x = match[((size_t)bon * 256 + t) * 128 + l];
  float m = x;
  for (int o = 32; o; o >>= 1) m = fmaxf(m, __shfl_xor(m, o, 64));
  if ((t & 63) == 0) redA[t >> 6] = m;
  __syncthreads();
  m = fmaxf(fmaxf(redA[0], redA[1]), fmaxf(redA[2], redA[3]));
  const float e = __expf(x - m);
  float s = e;
  for (int o = 32; o; o >>= 1) s += __shfl_xor(s, o, 64);
  if ((t & 63) == 0) redB[t >> 6] = s;
  __syncthreads();
  s = redB[0] + redB[1] + redB[2] + redB[3];
  qT[((size_t)bon * 128 + l) * 256 + t] = f2b(e / s);
}

// ---------------- gate, pool over N, output head, softmax over O ----------------
__global__ __launch_bounds__(256) void k_final(
    const float* __restrict__ s_r, const float* __restrict__ d_r,
    const u16* __restrict__ gw, const u16* __restrict__ gb,
    const u16* __restrict__ ow, const u16* __restrict__ ob,
    void* __restrict__ out, const int* __restrict__ flag) {
  __shared__ float coef[128];
  __shared__ float logits[16];
  const int t = threadIdx.x;
  if (t < 128) {
    float acc = bf2f(gb[0]);
    const float* sp = s_r + (size_t)t * 256;
    const float* dp = d_r + (size_t)t * 256;
    for (int d = 0; d < 256; ++d) acc += bf2f(gw[d]) * sp[d];
    for (int d = 0; d < 256; ++d) acc += bf2f(gw[256 + d]) * dp[d];
    coef[t] = acc;
  }
  __syncthreads();
  if (t < 16) {
    float acc = bf2f(ob[0]);
    for (int d = 0; d < 512; ++d) {
      float mx = -3.4e38f, sm = 0.f;
      for (int n = 0; n < 8; ++n) {
        const int bon = t * 8 + n;
        const float base = (d < 256) ? s_r[(size_t)bon * 256 + d] : d_r[(size_t)bon * 256 + (d - 256)];
        const float v = coef[bon] * base;
        mx = fmaxf(mx, v);
        sm += v;
      }
      acc += bf2f(ow[d]) * mx + bf2f(ow[512 + d]) * (sm * 0.125f);
    }
    logits[t] = acc;
  }
  __syncthreads();
  if (t < 4) {
    const int isf = *flag;
    float m = -3.4e38f;
    for (int o = 0; o < 4; ++o) m = fmaxf(m, logits[t * 4 + o]);
    float e[4], s = 0.f;
    for (int o = 0; o < 4; ++o) { e[o] = __expf(logits[t * 4 + o] - m); s += e[o]; }
    for (int o = 0; o < 4; ++o) {
      const float v = e[o] / s;
      if (isf) ((float*)out)[t * 4 + o] = v;
      else     ((u16*)out)[t * 4 + o] = f2b(v);
    }
  }
}

extern "C" void kernel_launch(void* const* d_in, const int* in_sizes, int n_in,
                              void* d_out, int out_size, void* d_ws, size_t ws_size,
                              hipStream_t stream) {
  (void)in_sizes; (void)n_in; (void)out_size; (void)ws_size;
  const void* statement = d_in[0];
  const void* answer    = d_in[1];
  const void* refs      = d_in[2];
  const void* ctx_wih = d_in[3];
  const void* ctx_whh = d_in[4];
  const void* ctx_bih = d_in[5];
  const void* ctx_bhh = d_in[6];
  const void* sr_wih = d_in[7];
  const void* sr_whh = d_in[8];
  const void* sr_bih = d_in[9];
  const void* sr_bhh = d_in[10];
  const void* dr_wih = d_in[11];
  const void* dr_whh = d_in[12];
  const void* dr_bih = d_in[13];
  const void* dr_bhh = d_in[14];
  const void* gate_w = d_in[15];
  const void* gate_b = d_in[16];
  const void* out_w  = d_in[17];
  const void* out_b  = d_in[18];

  char* ws = (char*)d_ws;
  size_t off = 0;
  auto alloc = [&](size_t bytes) -> void* {
    void* p = ws + off;
    off += (bytes + 255) & ~(size_t)255;
    return p;
  };
  // ---- region A: persistent (~37 MB) ----
  int* FLAG    = (int*)alloc(256);
  u16* CTXWIH  = (u16*)alloc((size_t)768 * 256 * 2);   // bf16 wih (GEMM operand)
  u16* SRWIH   = (u16*)alloc((size_t)768 * 256 * 2);
  u16* DRWIH   = (u16*)alloc((size_t)768 * 512 * 2);
  u32* CTXWHH2 = (u32*)alloc((size_t)128 * 768 * 4);   // fp16 half2, [k8][768][4] u32
  u32* SRWHH2  = (u32*)alloc((size_t)128 * 768 * 4);
  u32* DRWHH2  = (u32*)alloc((size_t)128 * 768 * 4);
  u16* B_CTX_I = (u16*)alloc(768 * 2);
  u16* B_CTX_H = (u16*)alloc(768 * 2);
  u16* B_SR_I  = (u16*)alloc(768 * 2);
  u16* B_SR_H  = (u16*)alloc(768 * 2);
  u16* B_DR_I  = (u16*)alloc(768 * 2);
  u16* B_DR_H  = (u16*)alloc(768 * 2);
  u16* GW = (u16*)alloc(512 * 2);
  u16* GB = (u16*)alloc(2);
  u16* OW = (u16*)alloc(1024 * 2);
  u16* OB = (u16*)alloc(2);
  u16* STMT_H   = (u16*)alloc((size_t)16 * 256 * 256 * 2);   // 2 MB  [bo][s][h]
  u16* DOCS_H   = (u16*)alloc((size_t)128 * 128 * 256 * 2);  // 8 MB  [bon][l][h]
  u16* DOC_READ = (u16*)alloc((size_t)128 * 128 * 256 * 2);  // 8 MB  [bon][l][h]
  u16* ATT      = (u16*)alloc((size_t)128 * 128 * 512 * 2);  // 16 MB [bon][l][2H]
  float* SR_R = (float*)alloc((size_t)128 * 256 * 4);
  float* DR_R = (float*)alloc((size_t)128 * 256 * 4);
  // ---- region B: 66 MB overlay, phase-disjoint lifetimes ----
  const size_t ovl = off;
  u16* REFS_B   = (u16*)(ws + ovl);                           // 8 MB   [phase 1]
  u16* STMT_IN  = (u16*)(ws + ovl + ((size_t)8 << 20));       // 2 MB   [phase 1]
  u16* XG_DOCS  = (u16*)(ws + ovl + ((size_t)16 << 20));      // 24 MB  [phase 1]
  u16* XG_STMT  = (u16*)(ws + ovl + ((size_t)41 << 20));      // 6 MB   [phase 1]
  float* MATCH  = (float*)(ws + ovl);                         // 16 MB  [phase 2]
  u16* P_ROW    = (u16*)(ws + ovl + ((size_t)16 << 20));      // 8 MB   [phase 2]
  u16* MATCH_Q  = (u16*)(ws + ovl + ((size_t)24 << 20));      // 8 MB   [phase 2]
  u16* READ_SUM = (u16*)(ws + ovl + ((size_t)50 << 20));      // 16 MB  [phase 2-3]
  u16* XG_SR    = (u16*)(ws + ovl);                           // 48 MB  [phase 3]
  float* MM     = (float*)(ws + ovl);                         // 64 MB  [phase 4]
  u16* XG_DR    = (u16*)(ws + ovl);                           // 24 MB  [phase 5]

  // 0) dtype detect
  k_detect<<<1, 64, 0, stream>>>(statement, FLAG);

  // 1) conversions / packing
  k_gather_stmt<<<4096, 256, 0, stream>>>(statement, answer, STMT_IN, FLAG);
  k_cvt<<<16384, 256, 0, stream>>>(refs, REFS_B, 4194304, FLAG);
  k_cvt<<<768, 256, 0, stream>>>(ctx_wih, CTXWIH, 196608, FLAG);
  k_cvt<<<768, 256, 0, stream>>>(sr_wih, SRWIH, 196608, FLAG);
  k_cvt<<<1536, 256, 0, stream>>>(dr_wih, DRWIH, 393216, FLAG);
  k_packh<<<384, 256, 0, stream>>>(ctx_whh, CTXWHH2, 98304, FLAG);
  k_packh<<<384, 256, 0, stream>>>(sr_whh, SRWHH2, 98304, FLAG);
  k_packh<<<384, 256, 0, stream>>>(dr_whh, DRWHH2, 98304, FLAG);
  k_cvt<<<3, 256, 0, stream>>>(ctx_bih, B_CTX_I, 768, FLAG);
  k_cvt<<<3, 256, 0, stream>>>(ctx_bhh, B_CTX_H, 768, FLAG);
  k_cvt<<<3, 256, 0, stream>>>(sr_bih, B_SR_I, 768, FLAG);
  k_cvt<<<3, 256, 0, stream>>>(sr_bhh, B_SR_H, 768, FLAG);
  k_cvt<<<3, 256, 0, stream>>>(dr_bih, B_DR_I, 768, FLAG);
  k_cvt<<<3, 256, 0, stream>>>(dr_bhh, B_DR_H, 768, FLAG);
  k_cvt<<<2, 256, 0, stream>>>(gate_w, GW, 512, FLAG);
  k_cvt<<<1, 256, 0, stream>>>(gate_b, GB, 1, FLAG);
  k_cvt<<<4, 256, 0, stream>>>(out_w, OW, 1024, FLAG);
  k_cvt<<<1, 256, 0, stream>>>(out_b, OB, 1, FLAG);

  // 2) ctx input projections: xg = X . wih^T  (M x 768, K=256)
  k_mgemm<true, false, u16, u16, u16><<<dim3(12, 64, 1), 256, 0, stream>>>(
      STMT_IN, 256, 0L, 1, CTXWIH, 256, 0L, 1, XG_STMT, 768, 0L, 256);
  k_mgemm<true, false, u16, u16, u16><<<dim3(12, 256, 1), 256, 0, stream>>>(
      REFS_B, 256, 0L, 1, CTXWIH, 256, 0L, 1, XG_DOCS, 768, 0L, 256);

  // 3) ctx GRUs, fused: stmt (16 seqs, T=256) + docs (128 seqs, T=128)
  k_rec<<<144, 768, 0, stream>>>(
      XG_STMT, CTXWHH2, B_CTX_I, B_CTX_H, STMT_H, nullptr, 16, 256,
      XG_DOCS, CTXWHH2, B_CTX_I, B_CTX_H, DOCS_H, nullptr, 128);

  // 4) match[bon][s][l] = stmt[bo] . docs[bon]^T  (M=256,N=128,K=256), fp32 out
  k_mgemm<true, false, u16, u16, float><<<dim3(2, 4, 128), 256, 0, stream>>>(
      STMT_H, 256, 65536L, 8, DOCS_H, 256, 32768L, 1, MATCH, 128, 32768L, 256);

  // 5) softmaxes from raw logits
  k_softmax_colT<<<dim3(128, 128), 256, 0, stream>>>(MATCH, MATCH_Q);
  k_softmax_row<float, u16><<<32768, 256, 0, stream>>>(MATCH, P_ROW, 128);

  // 6) read_sum[bon][s][h] = P_row . docs  (M=256,N=256,K=128), bf16 out
  k_mgemm<false, false, u16, u16, u16><<<dim3(4, 4, 128), 256, 0, stream>>>(
      P_ROW, 128, 32768L, 1, DOCS_H, 256, 32768L, 1, READ_SUM, 256, 65536L, 128);

  // 7) doc_read[bon][l][h] = MATCH_Q . stmt  (M=128,N=256,K=256) — before XG_SR overlay
  k_mgemm<false, false, u16, u16, u16><<<dim3(4, 2, 128), 256, 0, stream>>>(
      MATCH_Q, 256, 32768L, 1, STMT_H, 256, 65536L, 8, DOC_READ, 256, 32768L, 256);

  // 8) sr input projection: XG_SR = READ_SUM . sr_wih^T  (M=32768, K=256)
  k_mgemm<true, false, u16, u16, u16><<<dim3(12, 512, 1), 256, 0, stream>>>(
      READ_SUM, 256, 0L, 1, SRWIH, 256, 0L, 1, XG_SR, 768, 0L, 256);

  // 9) sr GRU (128 seqs, T=256), max-pooled
  k_rec<<<128, 768, 0, stream>>>(
      XG_SR, SRWHH2, B_SR_I, B_SR_H, nullptr, SR_R, 128, 256,
      nullptr, nullptr, nullptr, nullptr, nullptr, nullptr, 0);

  // 10) mm[bo][nl][m] = docs.docs^T + doc_read.doc_read^T  (M=N=1024,K=256 x2), fp32
  k_mgemm<true, false, u16, u16, float><<<dim3(16, 16, 16), 256, 0, stream>>>(
      DOCS_H, 256, 262144L, 1, DOCS_H, 256, 262144L, 1, MM, 1024, 1048576L, 256);
  k_mgemm<true, true, u16, u16, float><<<dim3(16, 16, 16), 256, 0, stream>>>(
      DOC_READ, 256, 262144L, 1, DOC_READ, 256, 262144L, 1, MM, 1024, 1048576L, 256);

  // 11) softmax over m, in place (fp32)
  k_softmax_row<float, float><<<16384, 256, 0, stream>>>(MM, MM, 1024);

  // 12) att[bon][l][0:256] = P . docs_flat ; [256:512] = P . doc_read_flat (bf16 out)
  k_mgemm<false, false, float, u16, u16><<<dim3(4, 16, 16), 256, 0, stream>>>(
      MM, 1024, 1048576L, 1, DOCS_H, 256, 262144L, 1, ATT, 512, 524288L, 1024);
  k_mgemm<false, false, float, u16, u16><<<dim3(4, 16, 16), 256, 0, stream>>>(
      MM, 1024, 1048576L, 1, DOC_READ, 256, 262144L, 1, ATT + 256, 512, 524288L, 1024);

  // 13) dr input projection: XG_DR = ATT . dr_wih^T  (M=16384, K=512) — MM dead
  k_mgemm<true, false, u16, u16, u16><<<dim3(12, 256, 1), 256, 0, stream>>>(
      ATT, 512, 0L, 1, DRWIH, 512, 0L, 1, XG_DR, 768, 0L, 512);

  // 14) dr GRU (128 seqs, T=128), max-pooled
  k_rec<<<128, 768, 0, stream>>>(
      XG_DR, DRWHH2, B_DR_I, B_DR_H, nullptr, DR_R, 128, 128,
      nullptr, nullptr, nullptr, nullptr, nullptr, nullptr, 0);

  // 15) gate + pool + head + softmax
  k_final<<<1, 256, 0, stream>>>(SR_R, DR_R, GW, GB, OW, OB, d_out, FLAG);
}